// Round 14
// baseline (251.016 us; speedup 1.0000x reference)
//
#include <hip/hip_runtime.h>

#define N_NODES 8192
#define N_EDGES 262144

typedef __attribute__((ext_vector_type(4))) float f32x4;
typedef _Float16 half8 __attribute__((ext_vector_type(8)));
typedef _Float16 half4v __attribute__((ext_vector_type(4)));
typedef __fp16 fp16x2 __attribute__((ext_vector_type(2)));
union UH { half8 h8; fp16x2 h2[4]; };
union HC { _Float16 h; unsigned short u; };

// ---------------- workspace zeroing (cnt only; scan zeroes cur) ----------------

__global__ void __launch_bounds__(256) zero_kernel(int4* __restrict__ p) {
  p[blockIdx.x * 256 + threadIdx.x] = make_int4(0, 0, 0, 0);
}

// ---------------- CSR build ----------------

__global__ void __launch_bounds__(1024) scan_kernel(const int* __restrict__ cnt,
                                                    int* __restrict__ rp,
                                                    float* __restrict__ dinv,
                                                    int* __restrict__ cur) {
  __shared__ int sums[1024];
  const int t = threadIdx.x;
  const int base = t * 8;
  int c[8];
  int s = 0;
#pragma unroll
  for (int i = 0; i < 8; ++i) { c[i] = cnt[base + i]; s += c[i]; cur[base + i] = 0; }
  sums[t] = s;
  __syncthreads();
  for (int off = 1; off < 1024; off <<= 1) {
    int v = (t >= off) ? sums[t - off] : 0;
    __syncthreads();
    sums[t] += v;
    __syncthreads();
  }
  int run = (t == 0) ? 0 : sums[t - 1];
#pragma unroll
  for (int i = 0; i < 8; ++i) {
    rp[base + i] = run;
    run += c[i];
    dinv[base + i] = rsqrtf((float)(c[i] + 1));
  }
  if (t == 1023) rp[N_NODES] = run;
}

__global__ void __launch_bounds__(256) fill_kernel(const int* __restrict__ src,
                                                   const int* __restrict__ dst,
                                                   const int* __restrict__ rp,
                                                   const float* __restrict__ dinv,
                                                   int* __restrict__ cur,
                                                   int* __restrict__ col,
                                                   float* __restrict__ wgt) {
  int e = blockIdx.x * 256 + threadIdx.x;
  int d = dst[e], s = src[e];
  int p = atomicAdd(&cur[d], 1);
  int at = rp[d] + p;
  col[at] = s;
  wgt[at] = dinv[s] * dinv[d];
}

// ---------------- dense matmul body (used by cm/het kernels) ----------------

template <int FIN, int FOUT, bool WT, bool BIAS, bool RELU, bool O16>
__device__ __forceinline__ void mm_body(const float* __restrict__ x,
                                        const float* __restrict__ w,
                                        const float* __restrict__ bias, void* out,
                                        int bx, int tid, float* ws, float* xs) {
  constexpr int VEC = (FOUT >= 32) ? 4 : 1;
  constexpr int TC = FOUT / VEC;
  constexpr int ROWS = 256 / TC;
  const int r0 = bx * ROWS;
  for (int i = tid; i < FIN * FOUT; i += 256) {
    int k = i / FOUT, j = i % FOUT;
    ws[i] = WT ? w[j * FIN + k] : w[i];
  }
  for (int i = tid; i < ROWS * FIN; i += 256) {
    int r = i / FIN, k = i % FIN;
    xs[r * (FIN + 1) + k] = x[(size_t)(r0 + r) * FIN + k];
  }
  __syncthreads();
  const int jc = tid % TC, r = tid / TC;
  float acc[VEC];
#pragma unroll
  for (int v = 0; v < VEC; ++v) acc[v] = 0.0f;
#pragma unroll
  for (int k = 0; k < FIN; ++k) {
    const float xv = xs[r * (FIN + 1) + k];
#pragma unroll
    for (int v = 0; v < VEC; ++v) acc[v] += xv * ws[k * FOUT + jc * VEC + v];
  }
  float oval[VEC];
#pragma unroll
  for (int v = 0; v < VEC; ++v) {
    int j = jc * VEC + v;
    float o = BIAS ? (acc[v] + bias[j]) : acc[v];
    if (RELU) o = fmaxf(o, 0.0f);
    oval[v] = o;
  }
  if constexpr (O16 && VEC == 4) {
    unsigned short* o16 = (unsigned short*)out;
    half4v pk;
#pragma unroll
    for (int v = 0; v < 4; ++v) pk[v] = (_Float16)oval[v];
    *(half4v*)&o16[(size_t)(r0 + r) * FOUT + jc * 4] = pk;
  } else {
    float* of = (float*)out;
#pragma unroll
    for (int v = 0; v < VEC; ++v) of[(size_t)(r0 + r) * FOUT + jc * VEC + v] = oval[v];
  }
}

// ---------------- GCN gather: wave gathers one node's row into LDS / global ----------------

template <int FIN, bool I16, bool GBR>
__device__ __forceinline__ void gather_row(const void* __restrict__ t,
                                           const int* __restrict__ rp,
                                           const int* __restrict__ col,
                                           const float* __restrict__ wgt,
                                           const float* __restrict__ dinv,
                                           const float* __restrict__ gbias,
                                           float* __restrict__ xrow, int n, int lane) {
  constexpr int FPL = I16 ? 8 : 4;
  constexpr int TPN = FIN / FPL;
  constexpr int EPI = 64 / TPN;
  const int eo = lane / TPN;
  const int fq = lane % TPN;
  const float di = dinv[n];
  const int rs = rp[n], re = rp[n + 1];
  float acc[FPL];
#pragma unroll
  for (int i = 0; i < FPL; ++i) acc[i] = 0.f;
  auto accum = [&](int node, float w) {
    if constexpr (I16) {
      const half8 hv = *(const half8*)((const unsigned short*)t + (size_t)node * FIN + fq * 8);
#pragma unroll
      for (int i = 0; i < 8; ++i) acc[i] += w * (float)hv[i];
    } else {
      const f32x4 v = *(const f32x4*)((const float*)t + (size_t)node * FIN + fq * 4);
#pragma unroll
      for (int i = 0; i < 4; ++i) acc[i] += w * v[i];
    }
  };
  if (eo == 0) accum(n, di * di);
  for (int e = rs + eo; e < re; e += EPI) accum(col[e], wgt[e]);
#pragma unroll
  for (int off = TPN; off < 64; off <<= 1) {
#pragma unroll
    for (int i = 0; i < FPL; ++i) acc[i] += __shfl_xor(acc[i], off, 64);
  }
  if (eo == 0) {
#pragma unroll
    for (int i = 0; i < FPL; ++i) {
      float v = acc[i];
      if (GBR) v = fmaxf(v + gbias[fq * FPL + i], 0.f);
      xrow[fq * FPL + i] = v;
    }
  }
}

// standalone gather body (agg4 + het1 gather side)
template <int F, bool BR, bool I16, bool O16>
__device__ __forceinline__ void aggv_body(const void* __restrict__ t,
                                          const int* __restrict__ rp,
                                          const int* __restrict__ col,
                                          const float* __restrict__ wgt,
                                          const float* __restrict__ dinv,
                                          const float* __restrict__ bias,
                                          void* __restrict__ out, int bx, int tid) {
  constexpr int FPL = I16 ? 8 : 4;
  constexpr int TPN = F / FPL;
  constexpr int EPI = 64 / TPN;
  const int wv = tid >> 6;
  const int lane = tid & 63;
  const int n = bx * 4 + wv;
  const int eo = lane / TPN;
  const int fq = lane % TPN;
  const float di = dinv[n];
  const int rs = rp[n], re = rp[n + 1];
  float acc[FPL];
#pragma unroll
  for (int i = 0; i < FPL; ++i) acc[i] = 0.f;
  auto accum = [&](int node, float w) {
    if constexpr (I16) {
      const half8 hv = *(const half8*)((const unsigned short*)t + (size_t)node * F + fq * 8);
#pragma unroll
      for (int i = 0; i < 8; ++i) acc[i] += w * (float)hv[i];
    } else {
      const f32x4 v = *(const f32x4*)((const float*)t + (size_t)node * F + fq * 4);
#pragma unroll
      for (int i = 0; i < 4; ++i) acc[i] += w * v[i];
    }
  };
  if (eo == 0) accum(n, di * di);
  for (int e = rs + eo; e < re; e += EPI) accum(col[e], wgt[e]);
#pragma unroll
  for (int off = TPN; off < 64; off <<= 1) {
#pragma unroll
    for (int i = 0; i < FPL; ++i) acc[i] += __shfl_xor(acc[i], off, 64);
  }
  if (eo == 0) {
    float r[FPL];
#pragma unroll
    for (int i = 0; i < FPL; ++i) {
      float v = acc[i];
      if (BR) v = fmaxf(v + bias[fq * FPL + i], 0.f);
      r[i] = v;
    }
    if constexpr (O16) {
      unsigned short* o = (unsigned short*)out;
      if constexpr (FPL == 8) {
        half8 pk;
#pragma unroll
        for (int i = 0; i < 8; ++i) pk[i] = (_Float16)r[i];
        *(half8*)&o[(size_t)n * F + fq * 8] = pk;
      } else {
        half4v p4;
#pragma unroll
        for (int i = 0; i < 4; ++i) p4[i] = (_Float16)r[i];
        *(half4v*)&o[(size_t)n * F + fq * 4] = p4;
      }
    } else {
      float* o = (float*)out;
#pragma unroll
      for (int i = 0; i < FPL; i += 4)
        *(f32x4*)&o[(size_t)n * F + fq * FPL + i] = f32x4{r[i], r[i + 1], r[i + 2], r[i + 3]};
    }
  }
}

template <int F, bool BR = true, bool I16 = false, bool O16 = false>
__global__ void __launch_bounds__(256) aggv_kernel(const void* __restrict__ t,
                                                   const int* __restrict__ rp,
                                                   const int* __restrict__ col,
                                                   const float* __restrict__ wgt,
                                                   const float* __restrict__ dinv,
                                                   const float* __restrict__ bias,
                                                   void* __restrict__ out) {
  aggv_body<F, BR, I16, O16>(t, rp, col, wgt, dinv, bias, out, blockIdx.x, threadIdx.x);
}

// ---------------- fused GCN layer: gather (4 nodes/block) -> LDS -> project ----------------

template <int FIN, int FOUT, bool GBR, bool PBIAS, bool PRELU, bool O16>
__device__ __forceinline__ void layer_body(const unsigned short* __restrict__ tin,
                                           const float* __restrict__ w,
                                           const float* __restrict__ gbias,
                                           const float* __restrict__ pbias,
                                           void* __restrict__ out, const int* rp,
                                           const int* col, const float* wgt,
                                           const float* dinv, int bx, int tid, float* ws,
                                           float* xrow) {
  for (int i = tid; i < FIN * FOUT; i += 256) ws[i] = w[i];
  const int wv = tid >> 6, lane = tid & 63;
  const int n0 = bx * 4;
  gather_row<FIN, true, GBR>(tin, rp, col, wgt, dinv, gbias, xrow + wv * FIN, n0 + wv, lane);
  __syncthreads();
  for (int idx = tid; idx < 4 * FOUT; idx += 256) {
    const int nn = idx / FOUT, j = idx % FOUT;
    float acc = PBIAS ? pbias[j] : 0.f;
    const float* xr = xrow + nn * FIN;
#pragma unroll
    for (int k = 0; k < FIN; ++k) acc += xr[k] * ws[k * FOUT + j];
    if (PRELU) acc = fmaxf(acc, 0.f);
    if constexpr (O16) {
      HC c;
      c.h = (_Float16)acc;
      ((unsigned short*)out)[(size_t)(n0 + nn) * FOUT + j] = c.u;
    } else {
      ((float*)out)[(size_t)(n0 + nn) * FOUT + j] = acc;
    }
  }
}

template <int FIN, int FOUT, bool GBR, bool PBIAS, bool PRELU, bool O16>
__global__ void __launch_bounds__(256) layer_kernel(const unsigned short* __restrict__ tin,
                                                    const float* __restrict__ w,
                                                    const float* __restrict__ gbias,
                                                    const float* __restrict__ pbias,
                                                    void* __restrict__ out,
                                                    const int* __restrict__ rp,
                                                    const int* __restrict__ col,
                                                    const float* __restrict__ wgt,
                                                    const float* __restrict__ dinv) {
  __shared__ float ws[FIN * FOUT];
  __shared__ float xrow[4 * FIN];
  layer_body<FIN, FOUT, GBR, PBIAS, PRELU, O16>(tin, w, gbias, pbias, out, rp, col, wgt,
                                                dinv, blockIdx.x, threadIdx.x, ws, xrow);
}

// F3: gather h3 + fused QKV projection (Q scaled, V transposed+kappa-swizzled)
__global__ void __launch_bounds__(256) agg_qkv_kernel(
    const unsigned short* __restrict__ t3, const float* __restrict__ b3,
    const float* __restrict__ wqkv, const float* __restrict__ bqkv,
    unsigned short* __restrict__ Q16, unsigned short* __restrict__ K16,
    unsigned short* __restrict__ V16, const int* __restrict__ rp,
    const int* __restrict__ col, const float* __restrict__ wgt,
    const float* __restrict__ dinv) {
  __shared__ float ws[32 * 96];
  __shared__ float xrow[4 * 32];
  const int tid = threadIdx.x;
  for (int i = tid; i < 3072; i += 256) {
    int k = i / 96, j = i % 96;
    ws[i] = wqkv[j * 32 + k];
  }
  const int wv = tid >> 6, lane = tid & 63;
  const int n0 = blockIdx.x * 4;
  gather_row<32, true, true>(t3, rp, col, wgt, dinv, b3, xrow + wv * 32, n0 + wv, lane);
  __syncthreads();
  const float QSCALE = 1.4426950408889634f * 0.17677669529663687f;  // log2e/sqrt(32)
  for (int idx = tid; idx < 384; idx += 256) {
    const int nn = idx / 96, j = idx % 96;
    const int row = n0 + nn;
    const float* xr = xrow + nn * 32;
    float acc = bqkv[j];
#pragma unroll
    for (int k = 0; k < 32; ++k) acc += xr[k] * ws[k * 96 + j];
    HC c;
    if (j < 32) {
      c.h = (_Float16)(acc * QSCALE);
      Q16[(size_t)row * 32 + j] = c.u;
    } else if (j < 64) {
      c.h = (_Float16)acc;
      K16[(size_t)row * 32 + (j - 32)] = c.u;
    } else {
      c.h = (_Float16)acc;
      const int ko = row & 31;
      const int slot = 8 * ((ko & 15) >> 2) + ((ko >> 4) << 2) + (ko & 3);
      V16[(size_t)(j - 64) * N_NODES + (row & ~31) + slot] = c.u;
    }
  }
}

// F5: shared raw gather of h4 + dual projection (w5a,w5f) -> fp16 tables
__global__ void __launch_bounds__(256) layer5_kernel(
    const unsigned short* __restrict__ h4, const float* __restrict__ w5a,
    const float* __restrict__ b5a, unsigned short* __restrict__ h5a,
    const float* __restrict__ w5f, const float* __restrict__ b5f,
    unsigned short* __restrict__ h5f, const int* __restrict__ rp,
    const int* __restrict__ col, const float* __restrict__ wgt,
    const float* __restrict__ dinv) {
  __shared__ float ws[2048];
  __shared__ float xrow[4 * 32];
  const int tid = threadIdx.x;
  for (int i = tid; i < 1024; i += 256) {
    ws[i] = w5a[i];
    ws[1024 + i] = w5f[i];
  }
  const int wv = tid >> 6, lane = tid & 63;
  const int n0 = blockIdx.x * 4;
  gather_row<32, true, false>(h4, rp, col, wgt, dinv, nullptr, xrow + wv * 32, n0 + wv, lane);
  __syncthreads();
  const int nn = tid >> 6;
  const int j = tid & 63;
  const int side = j >> 5, jj = j & 31;
  const float* xr = xrow + nn * 32;
  const float* wsd = ws + side * 1024;
  float acc = side ? b5f[jj] : b5a[jj];
#pragma unroll
  for (int k = 0; k < 32; ++k) acc += xr[k] * wsd[k * 32 + jj];
  acc = fmaxf(acc, 0.f);
  HC c;
  c.h = (_Float16)acc;
  unsigned short* o = side ? h5f : h5a;
  o[(size_t)(n0 + nn) * 32 + jj] = c.u;
}

// F6: dual-side fused L6 (A: h5a->h6a f32; B: h5f->h6f fp16)
__global__ void __launch_bounds__(256) layer6_kernel(
    const unsigned short* __restrict__ h5a, const float* __restrict__ w6a,
    const float* __restrict__ b6a, float* __restrict__ h6a,
    const unsigned short* __restrict__ h5f, const float* __restrict__ w6f,
    const float* __restrict__ b6f, unsigned short* __restrict__ h6f,
    const int* __restrict__ rp, const int* __restrict__ col,
    const float* __restrict__ wgt, const float* __restrict__ dinv) {
  __shared__ float ws[32 * 64];
  __shared__ float xrow[4 * 32];
  if (blockIdx.x < 2048)
    layer_body<32, 64, false, true, true, false>(h5a, w6a, nullptr, b6a, h6a, rp, col, wgt,
                                                 dinv, blockIdx.x, threadIdx.x, ws, xrow);
  else
    layer_body<32, 64, false, true, true, true>(h5f, w6f, nullptr, b6f, h6f, rp, col, wgt,
                                                dinv, blockIdx.x - 2048, threadIdx.x, ws, xrow);
}

// ---------------- hetero kernels ----------------

__global__ void __launch_bounds__(256) cm_kernel(const int* __restrict__ dst,
                                                 int* __restrict__ cnt,
                                                 const float* __restrict__ feat,
                                                 const float* __restrict__ w1,
                                                 unsigned short* __restrict__ T16) {
  __shared__ float ws[128 * 64];
  __shared__ float xs[16 * 129];
  if (blockIdx.x < 512) {
    mm_body<128, 64, false, false, false, true>(feat, w1, nullptr, T16, blockIdx.x,
                                                threadIdx.x, ws, xs);
  } else {
    int e = (blockIdx.x - 512) * 256 + threadIdx.x;
    atomicAdd(&cnt[dst[e]], 1);
  }
}

__global__ void __launch_bounds__(256) het1_kernel(
    const float* __restrict__ h6a, const float* __restrict__ w7a, float* __restrict__ pre7a,
    const unsigned short* __restrict__ h6f, float* __restrict__ g7f,
    const int* __restrict__ rp, const int* __restrict__ col,
    const float* __restrict__ wgt, const float* __restrict__ dinv) {
  __shared__ float ws[64 * 2];
  __shared__ float xs[128 * 65];
  if (blockIdx.x < 64)
    mm_body<64, 2, false, false, false, false>(h6a, w7a, nullptr, pre7a, blockIdx.x,
                                               threadIdx.x, ws, xs);
  else
    aggv_body<64, false, true, false>(h6f, rp, col, wgt, dinv, nullptr, g7f,
                                      blockIdx.x - 64, threadIdx.x);
}

__global__ void __launch_bounds__(256) het2_kernel(
    const float* __restrict__ pre7a, const float* __restrict__ b7a, float* __restrict__ outa,
    const float* __restrict__ g7f, const float* __restrict__ w7f,
    const float* __restrict__ b7f, float* __restrict__ outf,
    const int* __restrict__ rp, const int* __restrict__ col,
    const float* __restrict__ wgt, const float* __restrict__ dinv) {
  __shared__ float ws[64 * 128];
  __shared__ float xs[8 * 65];
  if (blockIdx.x < 64) {
    const int tid = threadIdx.x;
    const int n = blockIdx.x * 128 + tid / 2;
    const int f = tid & 1;
    const float di = dinv[n];
    float acc = di * di * pre7a[(size_t)n * 2 + f];
    const int rs = rp[n], re = rp[n + 1];
    for (int e = rs; e < re; ++e) {
      acc += wgt[e] * pre7a[(size_t)col[e] * 2 + f];
    }
    acc += b7a[f];
    outa[(size_t)n * 2 + f] = fmaxf(acc, 0.0f);
  } else {
    mm_body<64, 128, false, true, true, false>(g7f, w7f, b7f, outf, blockIdx.x - 64,
                                               threadIdx.x, ws, xs);
  }
}

// ---------------- MFMA flash attention: 2 q-tiles per wave, KSPLIT=8 ----------------
// grid (256 qpairs, 8 ranges) x 4 waves = 2048 blocks = 8 blocks/CU = 32 waves/CU (100%).
// launch_bounds(256,8): VGPR cap 64 (kernel measured 52 under cap 128 — no spill expected).

__device__ __forceinline__ void wave_writeout(float (*lds)[544], float (*wexp)[16],
                                              float* Mq, float* Lq, const f32x4& o1,
                                              const f32x4& o2, float m, float l, int wid,
                                              int g, int li, int tid, int qt, int by,
                                              float* __restrict__ part) {
#pragma unroll
  for (int r = 0; r < 4; ++r) {
    lds[wid][(4 * g + r) * 16 + li] = o1[r];
    lds[wid][(16 + 4 * g + r) * 16 + li] = o2[r];
  }
  if (g == 0) {
    lds[wid][512 + li] = m;
    lds[wid][528 + li] = l;
  }
  __syncthreads();
  if (tid < 16) {
    const int q = tid;
    const float m0 = lds[0][512 + q], m1 = lds[1][512 + q];
    const float m2 = lds[2][512 + q], m3 = lds[3][512 + q];
    const float M = fmaxf(fmaxf(m0, m1), fmaxf(m2, m3));
    const float w0 = exp2f(m0 - M), w1 = exp2f(m1 - M);
    const float w2 = exp2f(m2 - M), w3 = exp2f(m3 - M);
    wexp[0][q] = w0; wexp[1][q] = w1; wexp[2][q] = w2; wexp[3][q] = w3;
    Mq[q] = M;
    Lq[q] = w0 * lds[0][528 + q] + w1 * lds[1][528 + q] +
            w2 * lds[2][528 + q] + w3 * lds[3][528 + q];
  }
  __syncthreads();
  const int base = (qt * 8 + by) * 544;
#pragma unroll
  for (int e2 = 0; e2 < 2; ++e2) {
    const int e = tid + e2 * 256;
    const int q = e & 15;
    part[base + e] = wexp[0][q] * lds[0][e] + wexp[1][q] * lds[1][e] +
                     wexp[2][q] * lds[2][e] + wexp[3][q] * lds[3][e];
  }
  if (tid < 16) {
    part[base + 512 + tid] = Mq[tid];
    part[base + 528 + tid] = Lq[tid];
  }
}

__global__ void __launch_bounds__(256, 8) attn_mfma_kernel(
    const unsigned short* __restrict__ Q16, const unsigned short* __restrict__ K16,
    const unsigned short* __restrict__ V16, float* __restrict__ part) {
  __shared__ float lds[4][544];
  __shared__ float wexp[4][16];
  __shared__ float Mq[16], Lq[16];
  const int tid = threadIdx.x;
  const int wid = tid >> 6;
  const int lane = tid & 63;
  const int g = lane >> 4;
  const int li = lane & 15;
  const int qpair = blockIdx.x;
  const int q0A = qpair * 32;
  const int q0B = q0A + 16;
  const int kbeg = blockIdx.y * 1024 + wid * 256;

  const half8 qfA = *(const half8*)&Q16[(q0A + li) * 32 + 8 * g];
  const half8 qfB = *(const half8*)&Q16[(q0B + li) * 32 + 8 * g];
  const int koff = li * 32 + 8 * g;
  const int vA = li * N_NODES + 8 * g;
  const int vB = (16 + li) * N_NODES + 8 * g;

  f32x4 oAA = {0.f, 0.f, 0.f, 0.f}, oBA = {0.f, 0.f, 0.f, 0.f};
  f32x4 oAB = {0.f, 0.f, 0.f, 0.f}, oBB = {0.f, 0.f, 0.f, 0.f};
  float mA = -1e30f, lA = 0.f, mB = -1e30f, lB = 0.f;

  for (int t = kbeg; t < kbeg + 256; t += 64) {
    const half8 k0 = *(const half8*)&K16[(t)*32 + koff];
    const half8 k1 = *(const half8*)&K16[(t + 16) * 32 + koff];
    const half8 k2 = *(const half8*)&K16[(t + 32) * 32 + koff];
    const half8 k3 = *(const half8*)&K16[(t + 48) * 32 + koff];
    const half8 va0 = *(const half8*)&V16[vA + t];
    const half8 vb0 = *(const half8*)&V16[vB + t];
    const half8 va1 = *(const half8*)&V16[vA + t + 32];
    const half8 vb1 = *(const half8*)&V16[vB + t + 32];

    // ---- q-tile A ----
    {
      f32x4 s0 = {0.f, 0.f, 0.f, 0.f}, s1 = {0.f, 0.f, 0.f, 0.f};
      f32x4 s2 = {0.f, 0.f, 0.f, 0.f}, s3 = {0.f, 0.f, 0.f, 0.f};
      s0 = __builtin_amdgcn_mfma_f32_16x16x32_f16(k0, qfA, s0, 0, 0, 0);
      s1 = __builtin_amdgcn_mfma_f32_16x16x32_f16(k1, qfA, s1, 0, 0, 0);
      s2 = __builtin_amdgcn_mfma_f32_16x16x32_f16(k2, qfA, s2, 0, 0, 0);
      s3 = __builtin_amdgcn_mfma_f32_16x16x32_f16(k3, qfA, s3, 0, 0, 0);
      float mxl = fmaxf(fmaxf(fmaxf(s0[0], s0[1]), fmaxf(s0[2], s0[3])),
                        fmaxf(fmaxf(s1[0], s1[1]), fmaxf(s1[2], s1[3])));
      mxl = fmaxf(mxl, fmaxf(fmaxf(fmaxf(s2[0], s2[1]), fmaxf(s2[2], s2[3])),
                             fmaxf(fmaxf(s3[0], s3[1]), fmaxf(s3[2], s3[3]))));
      if (!__all(mxl <= mA)) {
        float mx = mxl;
        mx = fmaxf(mx, __shfl_xor(mx, 16, 64));
        mx = fmaxf(mx, __shfl_xor(mx, 32, 64));
        const float mn = fmaxf(mA, mx);
        const float fct = exp2f(mA - mn);
        oAA *= fct; oBA *= fct; lA *= fct;
        mA = mn;
      }
      const float p0 = exp2f(s0[0] - mA), p1 = exp2f(s0[1] - mA);
      const float p2 = exp2f(s0[2] - mA), p3 = exp2f(s0[3] - mA);
      const float p4 = exp2f(s1[0] - mA), p5 = exp2f(s1[1] - mA);
      const float p6 = exp2f(s1[2] - mA), p7 = exp2f(s1[3] - mA);
      const float p8 = exp2f(s2[0] - mA), p9 = exp2f(s2[1] - mA);
      const float pa = exp2f(s2[2] - mA), pb = exp2f(s2[3] - mA);
      const float pc = exp2f(s3[0] - mA), pd = exp2f(s3[1] - mA);
      const float pe = exp2f(s3[2] - mA), pf = exp2f(s3[3] - mA);
      lA += (((p0 + p1) + (p2 + p3)) + ((p4 + p5) + (p6 + p7))) +
            (((p8 + p9) + (pa + pb)) + ((pc + pd) + (pe + pf)));
      UH ph0, ph1;
      ph0.h2[0] = __builtin_amdgcn_cvt_pkrtz(p0, p1);
      ph0.h2[1] = __builtin_amdgcn_cvt_pkrtz(p2, p3);
      ph0.h2[2] = __builtin_amdgcn_cvt_pkrtz(p4, p5);
      ph0.h2[3] = __builtin_amdgcn_cvt_pkrtz(p6, p7);
      ph1.h2[0] = __builtin_amdgcn_cvt_pkrtz(p8, p9);
      ph1.h2[1] = __builtin_amdgcn_cvt_pkrtz(pa, pb);
      ph1.h2[2] = __builtin_amdgcn_cvt_pkrtz(pc, pd);
      ph1.h2[3] = __builtin_amdgcn_cvt_pkrtz(pe, pf);
      oAA = __builtin_amdgcn_mfma_f32_16x16x32_f16(va0, ph0.h8, oAA, 0, 0, 0);
      oAA = __builtin_amdgcn_mfma_f32_16x16x32_f16(va1, ph1.h8, oAA, 0, 0, 0);
      oBA = __builtin_amdgcn_mfma_f32_16x16x32_f16(vb0, ph0.h8, oBA, 0, 0, 0);
      oBA = __builtin_amdgcn_mfma_f32_16x16x32_f16(vb1, ph1.h8, oBA, 0, 0, 0);
    }
    // ---- q-tile B ----
    {
      f32x4 s0 = {0.f, 0.f, 0.f, 0.f}, s1 = {0.f, 0.f, 0.f, 0.f};
      f32x4 s2 = {0.f, 0.f, 0.f, 0.f}, s3 = {0.f, 0.f, 0.f, 0.f};
      s0 = __builtin_amdgcn_mfma_f32_16x16x32_f16(k0, qfB, s0, 0, 0, 0);
      s1 = __builtin_amdgcn_mfma_f32_16x16x32_f16(k1, qfB, s1, 0, 0, 0);
      s2 = __builtin_amdgcn_mfma_f32_16x16x32_f16(k2, qfB, s2, 0, 0, 0);
      s3 = __builtin_amdgcn_mfma_f32_16x16x32_f16(k3, qfB, s3, 0, 0, 0);
      float mxl = fmaxf(fmaxf(fmaxf(s0[0], s0[1]), fmaxf(s0[2], s0[3])),
                        fmaxf(fmaxf(s1[0], s1[1]), fmaxf(s1[2], s1[3])));
      mxl = fmaxf(mxl, fmaxf(fmaxf(fmaxf(s2[0], s2[1]), fmaxf(s2[2], s2[3])),
                             fmaxf(fmaxf(s3[0], s3[1]), fmaxf(s3[2], s3[3]))));
      if (!__all(mxl <= mB)) {
        float mx = mxl;
        mx = fmaxf(mx, __shfl_xor(mx, 16, 64));
        mx = fmaxf(mx, __shfl_xor(mx, 32, 64));
        const float mn = fmaxf(mB, mx);
        const float fct = exp2f(mB - mn);
        oAB *= fct; oBB *= fct; lB *= fct;
        mB = mn;
      }
      const float p0 = exp2f(s0[0] - mB), p1 = exp2f(s0[1] - mB);
      const float p2 = exp2f(s0[2] - mB), p3 = exp2f(s0[3] - mB);
      const float p4 = exp2f(s1[0] - mB), p5 = exp2f(s1[1] - mB);
      const float p6 = exp2f(s1[2] - mB), p7 = exp2f(s1[3] - mB);
      const float p8 = exp2f(s2[0] - mB), p9 = exp2f(s2[1] - mB);
      const float pa = exp2f(s2[2] - mB), pb = exp2f(s2[3] - mB);
      const float pc = exp2f(s3[0] - mB), pd = exp2f(s3[1] - mB);
      const float pe = exp2f(s3[2] - mB), pf = exp2f(s3[3] - mB);
      lB += (((p0 + p1) + (p2 + p3)) + ((p4 + p5) + (p6 + p7))) +
            (((p8 + p9) + (pa + pb)) + ((pc + pd) + (pe + pf)));
      UH ph0, ph1;
      ph0.h2[0] = __builtin_amdgcn_cvt_pkrtz(p0, p1);
      ph0.h2[1] = __builtin_amdgcn_cvt_pkrtz(p2, p3);
      ph0.h2[2] = __builtin_amdgcn_cvt_pkrtz(p4, p5);
      ph0.h2[3] = __builtin_amdgcn_cvt_pkrtz(p6, p7);
      ph1.h2[0] = __builtin_amdgcn_cvt_pkrtz(p8, p9);
      ph1.h2[1] = __builtin_amdgcn_cvt_pkrtz(pa, pb);
      ph1.h2[2] = __builtin_amdgcn_cvt_pkrtz(pc, pd);
      ph1.h2[3] = __builtin_amdgcn_cvt_pkrtz(pe, pf);
      oAB = __builtin_amdgcn_mfma_f32_16x16x32_f16(va0, ph0.h8, oAB, 0, 0, 0);
      oAB = __builtin_amdgcn_mfma_f32_16x16x32_f16(va1, ph1.h8, oAB, 0, 0, 0);
      oBB = __builtin_amdgcn_mfma_f32_16x16x32_f16(vb0, ph0.h8, oBB, 0, 0, 0);
      oBB = __builtin_amdgcn_mfma_f32_16x16x32_f16(vb1, ph1.h8, oBB, 0, 0, 0);
    }
  }

  lA += __shfl_xor(lA, 16, 64);
  lA += __shfl_xor(lA, 32, 64);
  lB += __shfl_xor(lB, 16, 64);
  lB += __shfl_xor(lB, 32, 64);

  wave_writeout(lds, wexp, Mq, Lq, oAA, oBA, mA, lA, wid, g, li, tid, qpair * 2,
                blockIdx.y, part);
  __syncthreads();
  wave_writeout(lds, wexp, Mq, Lq, oAB, oBB, mB, lB, wid, g, li, tid, qpair * 2 + 1,
                blockIdx.y, part);
}

// ---------------- combine 8 partials + fused wo AND w4 projections -> fp16 t4 ----------------

__global__ void __launch_bounds__(256) attn_combine_wo_w4(const float* __restrict__ part,
                                                          const float* __restrict__ wo,
                                                          const float* __restrict__ bo,
                                                          const float* __restrict__ w4,
                                                          unsigned short* __restrict__ T16out) {
  __shared__ float wols[1024];
  __shared__ float w4ls[1024];
  __shared__ float bos[32];
  __shared__ float aos[4][16][33];
  __shared__ float hs[4][16][33];
  const int tid = threadIdx.x;
  for (int i = tid; i < 1024; i += 256) {
    wols[i] = wo[i];
    w4ls[i] = w4[i];
  }
  if (tid < 32) bos[tid] = bo[tid];
  const int wv = tid >> 6, lane = tid & 63;
  const int qt = blockIdx.x * 4 + wv;
  const int q = lane & 15, g = lane >> 4;
  const int pb = qt * 8 * 544;
  float ms[8], w8[8];
  float M = -1e30f;
#pragma unroll
  for (int s = 0; s < 8; ++s) {
    ms[s] = part[pb + s * 544 + 512 + q];
    M = fmaxf(M, ms[s]);
  }
  float L = 0.f;
#pragma unroll
  for (int s = 0; s < 8; ++s) {
    w8[s] = exp2f(ms[s] - M);
    L += w8[s] * part[pb + s * 544 + 528 + q];
  }
  const float invL = 1.0f / L;
#pragma unroll
  for (int r = 0; r < 8; ++r) {
    const int d = g + 4 * r;
    const int o = d * 16 + q;
    float ov = 0.f;
#pragma unroll
    for (int s = 0; s < 8; ++s) ov += w8[s] * part[pb + s * 544 + o];
    aos[wv][q][d] = ov * invL;
  }
  __syncthreads();
#pragma unroll
  for (int r = 0; r < 8; ++r) {
    const int dout = g + 4 * r;
    float acc = bos[dout];
#pragma unroll
    for (int k = 0; k < 32; ++k) acc += aos[wv][q][k] * wols[dout * 32 + k];
    hs[wv][q][dout] = acc;
  }
#pragma unroll
  for (int r = 0; r < 8; ++r) {
    const int dout = g + 4 * r;
    float acc = 0.f;
#pragma unroll
    for (int k = 0; k < 32; ++k) acc += hs[wv][q][k] * w4ls[k * 32 + dout];
    HC c;
    c.h = (_Float16)acc;
    T16out[(size_t)(qt * 16 + q) * 32 + dout] = c.u;
  }
}

// ---------------- launch ----------------

extern "C" void kernel_launch(void* const* d_in, const int* in_sizes, int n_in,
                              void* d_out, int out_size, void* d_ws, size_t ws_size,
                              hipStream_t stream) {
  (void)in_sizes; (void)n_in; (void)out_size; (void)ws_size;
  const int* adj = (const int*)d_in[0];
  const float* feat = (const float*)d_in[1];
  const float* w1 = (const float*)d_in[2];  const float* b1 = (const float*)d_in[3];
  const float* w2 = (const float*)d_in[4];  const float* b2 = (const float*)d_in[5];
  const float* w3 = (const float*)d_in[6];  const float* b3 = (const float*)d_in[7];
  const float* wqkv = (const float*)d_in[8];const float* bqkv = (const float*)d_in[9];
  const float* wo = (const float*)d_in[10]; const float* bo = (const float*)d_in[11];
  const float* w4 = (const float*)d_in[12]; const float* b4 = (const float*)d_in[13];
  const float* w5a = (const float*)d_in[14];const float* b5a = (const float*)d_in[15];
  const float* w6a = (const float*)d_in[16];const float* b6a = (const float*)d_in[17];
  const float* w7a = (const float*)d_in[18];const float* b7a = (const float*)d_in[19];
  const float* w5f = (const float*)d_in[20];const float* b5f = (const float*)d_in[21];
  const float* w6f = (const float*)d_in[22];const float* b6f = (const float*)d_in[23];
  const float* w7f = (const float*)d_in[24];const float* b7f = (const float*)d_in[25];
  float* outp = (float*)d_out;

  float* wsf = (float*)d_ws;
  int* wsi = (int*)d_ws;
  int* cnt = wsi;                 // 8192
  int* cur = wsi + 8192;          // 8192 (zeroed by scan)
  int* rp = wsi + 16384;          // 8193
  float* dinv = wsf + 24832;      // 8192
  float* wgt = wsf + 33024;       // 262144
  int* col = wsi + 295168;        // 262144
  float* T = wsf + 557312;        // 8192*128 = 1048576 f32
  float* B0 = wsf + 1605888;      // 8192*64
  float* B1 = wsf + 2130176;      // 8192*32
  float* B2 = wsf + 2392320;      // 8192*64  (end 2916608)
  unsigned short* Q16 = (unsigned short*)(wsf + 2916608);
  unsigned short* K16 = Q16 + 262144;
  unsigned short* V16 = K16 + 262144;
  // T-region fp16 temps (all dead during attention; part overlays them)
  unsigned short* T16u = (unsigned short*)T;
  unsigned short* t1 = T16u;            // 8192x64
  unsigned short* t2 = T16u + 524288;   // 8192x32
  unsigned short* t3 = T16u;            // (t1 dead)
  unsigned short* B0h = (unsigned short*)B0;  // h4 fp16 table
  unsigned short* B1h = (unsigned short*)B1;  // h5a fp16 table
  unsigned short* B2h = (unsigned short*)B2;  // h5f fp16 table
  unsigned short* h6f = T16u;                 // 8192x64 fp16 (T free post-attn)
  float* g7f = T + 262144;                    // 8192x64 f32
  float* pre7a = B1;                          // 8192x2
  // attention partials: 512 qtiles x 8 ranges x 544 f32 = 2,228,224 f32
  // spans T..B2 [557312, 2785536) — all dead during attention
  float* part = T;
  // t4 sits in the B2 tail just past part: [2785536, 2916608) = 131072 f32 = 262144 ushorts
  unsigned short* t4 = (unsigned short*)(wsf + 2785536);

  const int* src = adj;
  const int* dst = adj + N_EDGES;

  zero_kernel<<<8, 256, 0, stream>>>((int4*)cnt);  // cnt (8192 ints)
  cm_kernel<<<1536, 256, 0, stream>>>(dst, cnt, feat, w1, t1);  // count || mm1
  scan_kernel<<<1, 1024, 0, stream>>>(cnt, rp, dinv, cur);      // also zeroes cur
  fill_kernel<<<N_EDGES / 256, 256, 0, stream>>>(src, dst, rp, dinv, cur, col, wgt);

  // F1 = agg1+mm2: h1 = relu(agg(t1)+b1); t2 = h1 @ w2 (fp16)
  layer_kernel<64, 32, true, false, false, true><<<N_NODES / 4, 256, 0, stream>>>(
      t1, w2, b1, nullptr, t2, rp, col, wgt, dinv);
  // F2 = agg2+mm3: h2 = relu(agg(t2)+b2); t3 = h2 @ w3 (fp16)
  layer_kernel<32, 32, true, false, false, true><<<N_NODES / 4, 256, 0, stream>>>(
      t2, w3, b2, nullptr, t3, rp, col, wgt, dinv);
  // F3 = agg3+qkv
  agg_qkv_kernel<<<N_NODES / 4, 256, 0, stream>>>(t3, b3, wqkv, bqkv, Q16, K16, V16, rp,
                                                  col, wgt, dinv);

  // attention: KSPLIT=8, 100% occupancy
  {
    dim3 grid(256, 8);
    attn_mfma_kernel<<<grid, 256, 0, stream>>>(Q16, K16, V16, part);
  }
  // combine(8) + wo + w4 fused -> t4 fp16
  attn_combine_wo_w4<<<128, 256, 0, stream>>>(part, wo, bo, w4, t4);

  // gcn4 gather: t4 -> h4 fp16 table
  aggv_kernel<32, true, true, true><<<N_NODES / 4, 256, 0, stream>>>(t4, rp, col, wgt,
                                                                     dinv, b4, B0h);

  // F5 = shared L5 gather + dual project
  layer5_kernel<<<N_NODES / 4, 256, 0, stream>>>(B0h, w5a, b5a, B1h, w5f, b5f, B2h, rp,
                                                 col, wgt, dinv);
  // F6 = dual L6
  layer6_kernel<<<2 * (N_NODES / 4), 256, 0, stream>>>(B1h, w6a, b6a, B0, B2h, w6f, b6f,
                                                       h6f, rp, col, wgt, dinv);
  // tails overlapped
  het1_kernel<<<64 + 2048, 256, 0, stream>>>(B0, w7a, pre7a, h6f, g7f, rp, col, wgt, dinv);
  het2_kernel<<<64 + 1024, 256, 0, stream>>>(pre7a, b7a, outp, g7f, w7f, b7f, outp + 16384,
                                             rp, col, wgt, dinv);
}

// Round 15
// 179.623 us; speedup vs baseline: 1.3975x; 1.3975x over previous
//
#include <hip/hip_runtime.h>

#define N_NODES 8192
#define N_EDGES 262144

typedef __attribute__((ext_vector_type(4))) float f32x4;
typedef _Float16 half8 __attribute__((ext_vector_type(8)));
typedef _Float16 half4v __attribute__((ext_vector_type(4)));
typedef __fp16 fp16x2 __attribute__((ext_vector_type(2)));
union UH { half8 h8; fp16x2 h2[4]; };
union HC { _Float16 h; unsigned short u; };

// ---------------- workspace zeroing (cnt only; scan zeroes cur) ----------------

__global__ void __launch_bounds__(256) zero_kernel(int4* __restrict__ p) {
  p[blockIdx.x * 256 + threadIdx.x] = make_int4(0, 0, 0, 0);
}

// ---------------- CSR build ----------------

__global__ void __launch_bounds__(1024) scan_kernel(const int* __restrict__ cnt,
                                                    int* __restrict__ rp,
                                                    float* __restrict__ dinv,
                                                    int* __restrict__ cur) {
  __shared__ int sums[1024];
  const int t = threadIdx.x;
  const int base = t * 8;
  int c[8];
  int s = 0;
#pragma unroll
  for (int i = 0; i < 8; ++i) { c[i] = cnt[base + i]; s += c[i]; cur[base + i] = 0; }
  sums[t] = s;
  __syncthreads();
  for (int off = 1; off < 1024; off <<= 1) {
    int v = (t >= off) ? sums[t - off] : 0;
    __syncthreads();
    sums[t] += v;
    __syncthreads();
  }
  int run = (t == 0) ? 0 : sums[t - 1];
#pragma unroll
  for (int i = 0; i < 8; ++i) {
    rp[base + i] = run;
    run += c[i];
    dinv[base + i] = rsqrtf((float)(c[i] + 1));
  }
  if (t == 1023) rp[N_NODES] = run;
}

__global__ void __launch_bounds__(256) fill_kernel(const int* __restrict__ src,
                                                   const int* __restrict__ dst,
                                                   const int* __restrict__ rp,
                                                   const float* __restrict__ dinv,
                                                   int* __restrict__ cur,
                                                   int* __restrict__ col,
                                                   float* __restrict__ wgt) {
  int e = blockIdx.x * 256 + threadIdx.x;
  int d = dst[e], s = src[e];
  int p = atomicAdd(&cur[d], 1);
  int at = rp[d] + p;
  col[at] = s;
  wgt[at] = dinv[s] * dinv[d];
}

// ---------------- dense matmul body (used by cm/het kernels) ----------------

template <int FIN, int FOUT, bool WT, bool BIAS, bool RELU, bool O16>
__device__ __forceinline__ void mm_body(const float* __restrict__ x,
                                        const float* __restrict__ w,
                                        const float* __restrict__ bias, void* out,
                                        int bx, int tid, float* ws, float* xs) {
  constexpr int VEC = (FOUT >= 32) ? 4 : 1;
  constexpr int TC = FOUT / VEC;
  constexpr int ROWS = 256 / TC;
  const int r0 = bx * ROWS;
  for (int i = tid; i < FIN * FOUT; i += 256) {
    int k = i / FOUT, j = i % FOUT;
    ws[i] = WT ? w[j * FIN + k] : w[i];
  }
  for (int i = tid; i < ROWS * FIN; i += 256) {
    int r = i / FIN, k = i % FIN;
    xs[r * (FIN + 1) + k] = x[(size_t)(r0 + r) * FIN + k];
  }
  __syncthreads();
  const int jc = tid % TC, r = tid / TC;
  float acc[VEC];
#pragma unroll
  for (int v = 0; v < VEC; ++v) acc[v] = 0.0f;
#pragma unroll
  for (int k = 0; k < FIN; ++k) {
    const float xv = xs[r * (FIN + 1) + k];
#pragma unroll
    for (int v = 0; v < VEC; ++v) acc[v] += xv * ws[k * FOUT + jc * VEC + v];
  }
  float oval[VEC];
#pragma unroll
  for (int v = 0; v < VEC; ++v) {
    int j = jc * VEC + v;
    float o = BIAS ? (acc[v] + bias[j]) : acc[v];
    if (RELU) o = fmaxf(o, 0.0f);
    oval[v] = o;
  }
  if constexpr (O16 && VEC == 4) {
    unsigned short* o16 = (unsigned short*)out;
    half4v pk;
#pragma unroll
    for (int v = 0; v < 4; ++v) pk[v] = (_Float16)oval[v];
    *(half4v*)&o16[(size_t)(r0 + r) * FOUT + jc * 4] = pk;
  } else {
    float* of = (float*)out;
#pragma unroll
    for (int v = 0; v < VEC; ++v) of[(size_t)(r0 + r) * FOUT + jc * VEC + v] = oval[v];
  }
}

// ---------------- GCN gather: wave gathers one node's row into LDS / global ----------------

template <int FIN, bool I16, bool GBR>
__device__ __forceinline__ void gather_row(const void* __restrict__ t,
                                           const int* __restrict__ rp,
                                           const int* __restrict__ col,
                                           const float* __restrict__ wgt,
                                           const float* __restrict__ dinv,
                                           const float* __restrict__ gbias,
                                           float* __restrict__ xrow, int n, int lane) {
  constexpr int FPL = I16 ? 8 : 4;
  constexpr int TPN = FIN / FPL;
  constexpr int EPI = 64 / TPN;
  const int eo = lane / TPN;
  const int fq = lane % TPN;
  const float di = dinv[n];
  const int rs = rp[n], re = rp[n + 1];
  float acc[FPL];
#pragma unroll
  for (int i = 0; i < FPL; ++i) acc[i] = 0.f;
  auto accum = [&](int node, float w) {
    if constexpr (I16) {
      const half8 hv = *(const half8*)((const unsigned short*)t + (size_t)node * FIN + fq * 8);
#pragma unroll
      for (int i = 0; i < 8; ++i) acc[i] += w * (float)hv[i];
    } else {
      const f32x4 v = *(const f32x4*)((const float*)t + (size_t)node * FIN + fq * 4);
#pragma unroll
      for (int i = 0; i < 4; ++i) acc[i] += w * v[i];
    }
  };
  if (eo == 0) accum(n, di * di);
  for (int e = rs + eo; e < re; e += EPI) accum(col[e], wgt[e]);
#pragma unroll
  for (int off = TPN; off < 64; off <<= 1) {
#pragma unroll
    for (int i = 0; i < FPL; ++i) acc[i] += __shfl_xor(acc[i], off, 64);
  }
  if (eo == 0) {
#pragma unroll
    for (int i = 0; i < FPL; ++i) {
      float v = acc[i];
      if (GBR) v = fmaxf(v + gbias[fq * FPL + i], 0.f);
      xrow[fq * FPL + i] = v;
    }
  }
}

// standalone gather body (agg4 + het1 gather side)
template <int F, bool BR, bool I16, bool O16>
__device__ __forceinline__ void aggv_body(const void* __restrict__ t,
                                          const int* __restrict__ rp,
                                          const int* __restrict__ col,
                                          const float* __restrict__ wgt,
                                          const float* __restrict__ dinv,
                                          const float* __restrict__ bias,
                                          void* __restrict__ out, int bx, int tid) {
  constexpr int FPL = I16 ? 8 : 4;
  constexpr int TPN = F / FPL;
  constexpr int EPI = 64 / TPN;
  const int wv = tid >> 6;
  const int lane = tid & 63;
  const int n = bx * 4 + wv;
  const int eo = lane / TPN;
  const int fq = lane % TPN;
  const float di = dinv[n];
  const int rs = rp[n], re = rp[n + 1];
  float acc[FPL];
#pragma unroll
  for (int i = 0; i < FPL; ++i) acc[i] = 0.f;
  auto accum = [&](int node, float w) {
    if constexpr (I16) {
      const half8 hv = *(const half8*)((const unsigned short*)t + (size_t)node * F + fq * 8);
#pragma unroll
      for (int i = 0; i < 8; ++i) acc[i] += w * (float)hv[i];
    } else {
      const f32x4 v = *(const f32x4*)((const float*)t + (size_t)node * F + fq * 4);
#pragma unroll
      for (int i = 0; i < 4; ++i) acc[i] += w * v[i];
    }
  };
  if (eo == 0) accum(n, di * di);
  for (int e = rs + eo; e < re; e += EPI) accum(col[e], wgt[e]);
#pragma unroll
  for (int off = TPN; off < 64; off <<= 1) {
#pragma unroll
    for (int i = 0; i < FPL; ++i) acc[i] += __shfl_xor(acc[i], off, 64);
  }
  if (eo == 0) {
    float r[FPL];
#pragma unroll
    for (int i = 0; i < FPL; ++i) {
      float v = acc[i];
      if (BR) v = fmaxf(v + bias[fq * FPL + i], 0.f);
      r[i] = v;
    }
    if constexpr (O16) {
      unsigned short* o = (unsigned short*)out;
      if constexpr (FPL == 8) {
        half8 pk;
#pragma unroll
        for (int i = 0; i < 8; ++i) pk[i] = (_Float16)r[i];
        *(half8*)&o[(size_t)n * F + fq * 8] = pk;
      } else {
        half4v p4;
#pragma unroll
        for (int i = 0; i < 4; ++i) p4[i] = (_Float16)r[i];
        *(half4v*)&o[(size_t)n * F + fq * 4] = p4;
      }
    } else {
      float* o = (float*)out;
#pragma unroll
      for (int i = 0; i < FPL; i += 4)
        *(f32x4*)&o[(size_t)n * F + fq * FPL + i] = f32x4{r[i], r[i + 1], r[i + 2], r[i + 3]};
    }
  }
}

template <int F, bool BR = true, bool I16 = false, bool O16 = false>
__global__ void __launch_bounds__(256) aggv_kernel(const void* __restrict__ t,
                                                   const int* __restrict__ rp,
                                                   const int* __restrict__ col,
                                                   const float* __restrict__ wgt,
                                                   const float* __restrict__ dinv,
                                                   const float* __restrict__ bias,
                                                   void* __restrict__ out) {
  aggv_body<F, BR, I16, O16>(t, rp, col, wgt, dinv, bias, out, blockIdx.x, threadIdx.x);
}

// ---------------- fused GCN layer: gather (4 nodes/block) -> LDS -> project ----------------

template <int FIN, int FOUT, bool GBR, bool PBIAS, bool PRELU, bool O16>
__device__ __forceinline__ void layer_body(const unsigned short* __restrict__ tin,
                                           const float* __restrict__ w,
                                           const float* __restrict__ gbias,
                                           const float* __restrict__ pbias,
                                           void* __restrict__ out, const int* rp,
                                           const int* col, const float* wgt,
                                           const float* dinv, int bx, int tid, float* ws,
                                           float* xrow) {
  for (int i = tid; i < FIN * FOUT; i += 256) ws[i] = w[i];
  const int wv = tid >> 6, lane = tid & 63;
  const int n0 = bx * 4;
  gather_row<FIN, true, GBR>(tin, rp, col, wgt, dinv, gbias, xrow + wv * FIN, n0 + wv, lane);
  __syncthreads();
  for (int idx = tid; idx < 4 * FOUT; idx += 256) {
    const int nn = idx / FOUT, j = idx % FOUT;
    float acc = PBIAS ? pbias[j] : 0.f;
    const float* xr = xrow + nn * FIN;
#pragma unroll
    for (int k = 0; k < FIN; ++k) acc += xr[k] * ws[k * FOUT + j];
    if (PRELU) acc = fmaxf(acc, 0.f);
    if constexpr (O16) {
      HC c;
      c.h = (_Float16)acc;
      ((unsigned short*)out)[(size_t)(n0 + nn) * FOUT + j] = c.u;
    } else {
      ((float*)out)[(size_t)(n0 + nn) * FOUT + j] = acc;
    }
  }
}

template <int FIN, int FOUT, bool GBR, bool PBIAS, bool PRELU, bool O16>
__global__ void __launch_bounds__(256) layer_kernel(const unsigned short* __restrict__ tin,
                                                    const float* __restrict__ w,
                                                    const float* __restrict__ gbias,
                                                    const float* __restrict__ pbias,
                                                    void* __restrict__ out,
                                                    const int* __restrict__ rp,
                                                    const int* __restrict__ col,
                                                    const float* __restrict__ wgt,
                                                    const float* __restrict__ dinv) {
  __shared__ float ws[FIN * FOUT];
  __shared__ float xrow[4 * FIN];
  layer_body<FIN, FOUT, GBR, PBIAS, PRELU, O16>(tin, w, gbias, pbias, out, rp, col, wgt,
                                                dinv, blockIdx.x, threadIdx.x, ws, xrow);
}

// F3: gather h3 + fused QKV projection (Q scaled, V transposed+kappa-swizzled)
__global__ void __launch_bounds__(256) agg_qkv_kernel(
    const unsigned short* __restrict__ t3, const float* __restrict__ b3,
    const float* __restrict__ wqkv, const float* __restrict__ bqkv,
    unsigned short* __restrict__ Q16, unsigned short* __restrict__ K16,
    unsigned short* __restrict__ V16, const int* __restrict__ rp,
    const int* __restrict__ col, const float* __restrict__ wgt,
    const float* __restrict__ dinv) {
  __shared__ float ws[32 * 96];
  __shared__ float xrow[4 * 32];
  const int tid = threadIdx.x;
  for (int i = tid; i < 3072; i += 256) {
    int k = i / 96, j = i % 96;
    ws[i] = wqkv[j * 32 + k];
  }
  const int wv = tid >> 6, lane = tid & 63;
  const int n0 = blockIdx.x * 4;
  gather_row<32, true, true>(t3, rp, col, wgt, dinv, b3, xrow + wv * 32, n0 + wv, lane);
  __syncthreads();
  const float QSCALE = 1.4426950408889634f * 0.17677669529663687f;  // log2e/sqrt(32)
  for (int idx = tid; idx < 384; idx += 256) {
    const int nn = idx / 96, j = idx % 96;
    const int row = n0 + nn;
    const float* xr = xrow + nn * 32;
    float acc = bqkv[j];
#pragma unroll
    for (int k = 0; k < 32; ++k) acc += xr[k] * ws[k * 96 + j];
    HC c;
    if (j < 32) {
      c.h = (_Float16)(acc * QSCALE);
      Q16[(size_t)row * 32 + j] = c.u;
    } else if (j < 64) {
      c.h = (_Float16)acc;
      K16[(size_t)row * 32 + (j - 32)] = c.u;
    } else {
      c.h = (_Float16)acc;
      const int ko = row & 31;
      const int slot = 8 * ((ko & 15) >> 2) + ((ko >> 4) << 2) + (ko & 3);
      V16[(size_t)(j - 64) * N_NODES + (row & ~31) + slot] = c.u;
    }
  }
}

// F5: shared raw gather of h4 + dual projection (w5a,w5f) -> fp16 tables
__global__ void __launch_bounds__(256) layer5_kernel(
    const unsigned short* __restrict__ h4, const float* __restrict__ w5a,
    const float* __restrict__ b5a, unsigned short* __restrict__ h5a,
    const float* __restrict__ w5f, const float* __restrict__ b5f,
    unsigned short* __restrict__ h5f, const int* __restrict__ rp,
    const int* __restrict__ col, const float* __restrict__ wgt,
    const float* __restrict__ dinv) {
  __shared__ float ws[2048];
  __shared__ float xrow[4 * 32];
  const int tid = threadIdx.x;
  for (int i = tid; i < 1024; i += 256) {
    ws[i] = w5a[i];
    ws[1024 + i] = w5f[i];
  }
  const int wv = tid >> 6, lane = tid & 63;
  const int n0 = blockIdx.x * 4;
  gather_row<32, true, false>(h4, rp, col, wgt, dinv, nullptr, xrow + wv * 32, n0 + wv, lane);
  __syncthreads();
  const int nn = tid >> 6;
  const int j = tid & 63;
  const int side = j >> 5, jj = j & 31;
  const float* xr = xrow + nn * 32;
  const float* wsd = ws + side * 1024;
  float acc = side ? b5f[jj] : b5a[jj];
#pragma unroll
  for (int k = 0; k < 32; ++k) acc += xr[k] * wsd[k * 32 + jj];
  acc = fmaxf(acc, 0.f);
  HC c;
  c.h = (_Float16)acc;
  unsigned short* o = side ? h5f : h5a;
  o[(size_t)(n0 + nn) * 32 + jj] = c.u;
}

// F6: dual-side fused L6 (A: h5a->h6a f32; B: h5f->h6f fp16)
__global__ void __launch_bounds__(256) layer6_kernel(
    const unsigned short* __restrict__ h5a, const float* __restrict__ w6a,
    const float* __restrict__ b6a, float* __restrict__ h6a,
    const unsigned short* __restrict__ h5f, const float* __restrict__ w6f,
    const float* __restrict__ b6f, unsigned short* __restrict__ h6f,
    const int* __restrict__ rp, const int* __restrict__ col,
    const float* __restrict__ wgt, const float* __restrict__ dinv) {
  __shared__ float ws[32 * 64];
  __shared__ float xrow[4 * 32];
  if (blockIdx.x < 2048)
    layer_body<32, 64, false, true, true, false>(h5a, w6a, nullptr, b6a, h6a, rp, col, wgt,
                                                 dinv, blockIdx.x, threadIdx.x, ws, xrow);
  else
    layer_body<32, 64, false, true, true, true>(h5f, w6f, nullptr, b6f, h6f, rp, col, wgt,
                                                dinv, blockIdx.x - 2048, threadIdx.x, ws, xrow);
}

// ---------------- hetero kernels ----------------

__global__ void __launch_bounds__(256) cm_kernel(const int* __restrict__ dst,
                                                 int* __restrict__ cnt,
                                                 const float* __restrict__ feat,
                                                 const float* __restrict__ w1,
                                                 unsigned short* __restrict__ T16) {
  __shared__ float ws[128 * 64];
  __shared__ float xs[16 * 129];
  if (blockIdx.x < 512) {
    mm_body<128, 64, false, false, false, true>(feat, w1, nullptr, T16, blockIdx.x,
                                                threadIdx.x, ws, xs);
  } else {
    int e = (blockIdx.x - 512) * 256 + threadIdx.x;
    atomicAdd(&cnt[dst[e]], 1);
  }
}

__global__ void __launch_bounds__(256) het1_kernel(
    const float* __restrict__ h6a, const float* __restrict__ w7a, float* __restrict__ pre7a,
    const unsigned short* __restrict__ h6f, float* __restrict__ g7f,
    const int* __restrict__ rp, const int* __restrict__ col,
    const float* __restrict__ wgt, const float* __restrict__ dinv) {
  __shared__ float ws[64 * 2];
  __shared__ float xs[128 * 65];
  if (blockIdx.x < 64)
    mm_body<64, 2, false, false, false, false>(h6a, w7a, nullptr, pre7a, blockIdx.x,
                                               threadIdx.x, ws, xs);
  else
    aggv_body<64, false, true, false>(h6f, rp, col, wgt, dinv, nullptr, g7f,
                                      blockIdx.x - 64, threadIdx.x);
}

__global__ void __launch_bounds__(256) het2_kernel(
    const float* __restrict__ pre7a, const float* __restrict__ b7a, float* __restrict__ outa,
    const float* __restrict__ g7f, const float* __restrict__ w7f,
    const float* __restrict__ b7f, float* __restrict__ outf,
    const int* __restrict__ rp, const int* __restrict__ col,
    const float* __restrict__ wgt, const float* __restrict__ dinv) {
  __shared__ float ws[64 * 128];
  __shared__ float xs[8 * 65];
  if (blockIdx.x < 64) {
    const int tid = threadIdx.x;
    const int n = blockIdx.x * 128 + tid / 2;
    const int f = tid & 1;
    const float di = dinv[n];
    float acc = di * di * pre7a[(size_t)n * 2 + f];
    const int rs = rp[n], re = rp[n + 1];
    for (int e = rs; e < re; ++e) {
      acc += wgt[e] * pre7a[(size_t)col[e] * 2 + f];
    }
    acc += b7a[f];
    outa[(size_t)n * 2 + f] = fmaxf(acc, 0.0f);
  } else {
    mm_body<64, 128, false, true, true, false>(g7f, w7f, b7f, outf, blockIdx.x - 64,
                                               threadIdx.x, ws, xs);
  }
}

// ---------------- MFMA flash attention: 2 q-tiles per wave, KSPLIT=8 ----------------
// grid (256 qpairs, 8 ranges) x 4 waves = 2048 blocks = 8 blocks/CU.
// launch_bounds(256,4): VGPR cap 128 -> compiler uses ~52, NO spill; HW still
// co-schedules 8 waves/SIMD at 52 VGPR (8x52=416 <= 512). r14's (256,8) cap=64 spilled.

__device__ __forceinline__ void wave_writeout(float (*lds)[544], float (*wexp)[16],
                                              float* Mq, float* Lq, const f32x4& o1,
                                              const f32x4& o2, float m, float l, int wid,
                                              int g, int li, int tid, int qt, int by,
                                              float* __restrict__ part) {
#pragma unroll
  for (int r = 0; r < 4; ++r) {
    lds[wid][(4 * g + r) * 16 + li] = o1[r];
    lds[wid][(16 + 4 * g + r) * 16 + li] = o2[r];
  }
  if (g == 0) {
    lds[wid][512 + li] = m;
    lds[wid][528 + li] = l;
  }
  __syncthreads();
  if (tid < 16) {
    const int q = tid;
    const float m0 = lds[0][512 + q], m1 = lds[1][512 + q];
    const float m2 = lds[2][512 + q], m3 = lds[3][512 + q];
    const float M = fmaxf(fmaxf(m0, m1), fmaxf(m2, m3));
    const float w0 = exp2f(m0 - M), w1 = exp2f(m1 - M);
    const float w2 = exp2f(m2 - M), w3 = exp2f(m3 - M);
    wexp[0][q] = w0; wexp[1][q] = w1; wexp[2][q] = w2; wexp[3][q] = w3;
    Mq[q] = M;
    Lq[q] = w0 * lds[0][528 + q] + w1 * lds[1][528 + q] +
            w2 * lds[2][528 + q] + w3 * lds[3][528 + q];
  }
  __syncthreads();
  const int base = (qt * 8 + by) * 544;
#pragma unroll
  for (int e2 = 0; e2 < 2; ++e2) {
    const int e = tid + e2 * 256;
    const int q = e & 15;
    part[base + e] = wexp[0][q] * lds[0][e] + wexp[1][q] * lds[1][e] +
                     wexp[2][q] * lds[2][e] + wexp[3][q] * lds[3][e];
  }
  if (tid < 16) {
    part[base + 512 + tid] = Mq[tid];
    part[base + 528 + tid] = Lq[tid];
  }
}

__global__ void __launch_bounds__(256, 4) attn_mfma_kernel(
    const unsigned short* __restrict__ Q16, const unsigned short* __restrict__ K16,
    const unsigned short* __restrict__ V16, float* __restrict__ part) {
  __shared__ float lds[4][544];
  __shared__ float wexp[4][16];
  __shared__ float Mq[16], Lq[16];
  const int tid = threadIdx.x;
  const int wid = tid >> 6;
  const int lane = tid & 63;
  const int g = lane >> 4;
  const int li = lane & 15;
  const int qpair = blockIdx.x;
  const int q0A = qpair * 32;
  const int q0B = q0A + 16;
  const int kbeg = blockIdx.y * 1024 + wid * 256;

  const half8 qfA = *(const half8*)&Q16[(q0A + li) * 32 + 8 * g];
  const half8 qfB = *(const half8*)&Q16[(q0B + li) * 32 + 8 * g];
  const int koff = li * 32 + 8 * g;
  const int vA = li * N_NODES + 8 * g;
  const int vB = (16 + li) * N_NODES + 8 * g;

  f32x4 oAA = {0.f, 0.f, 0.f, 0.f}, oBA = {0.f, 0.f, 0.f, 0.f};
  f32x4 oAB = {0.f, 0.f, 0.f, 0.f}, oBB = {0.f, 0.f, 0.f, 0.f};
  float mA = -1e30f, lA = 0.f, mB = -1e30f, lB = 0.f;

  for (int t = kbeg; t < kbeg + 256; t += 64) {
    const half8 k0 = *(const half8*)&K16[(t)*32 + koff];
    const half8 k1 = *(const half8*)&K16[(t + 16) * 32 + koff];
    const half8 k2 = *(const half8*)&K16[(t + 32) * 32 + koff];
    const half8 k3 = *(const half8*)&K16[(t + 48) * 32 + koff];
    const half8 va0 = *(const half8*)&V16[vA + t];
    const half8 vb0 = *(const half8*)&V16[vB + t];
    const half8 va1 = *(const half8*)&V16[vA + t + 32];
    const half8 vb1 = *(const half8*)&V16[vB + t + 32];

    // ---- q-tile A ----
    {
      f32x4 s0 = {0.f, 0.f, 0.f, 0.f}, s1 = {0.f, 0.f, 0.f, 0.f};
      f32x4 s2 = {0.f, 0.f, 0.f, 0.f}, s3 = {0.f, 0.f, 0.f, 0.f};
      s0 = __builtin_amdgcn_mfma_f32_16x16x32_f16(k0, qfA, s0, 0, 0, 0);
      s1 = __builtin_amdgcn_mfma_f32_16x16x32_f16(k1, qfA, s1, 0, 0, 0);
      s2 = __builtin_amdgcn_mfma_f32_16x16x32_f16(k2, qfA, s2, 0, 0, 0);
      s3 = __builtin_amdgcn_mfma_f32_16x16x32_f16(k3, qfA, s3, 0, 0, 0);
      float mxl = fmaxf(fmaxf(fmaxf(s0[0], s0[1]), fmaxf(s0[2], s0[3])),
                        fmaxf(fmaxf(s1[0], s1[1]), fmaxf(s1[2], s1[3])));
      mxl = fmaxf(mxl, fmaxf(fmaxf(fmaxf(s2[0], s2[1]), fmaxf(s2[2], s2[3])),
                             fmaxf(fmaxf(s3[0], s3[1]), fmaxf(s3[2], s3[3]))));
      if (!__all(mxl <= mA)) {
        float mx = mxl;
        mx = fmaxf(mx, __shfl_xor(mx, 16, 64));
        mx = fmaxf(mx, __shfl_xor(mx, 32, 64));
        const float mn = fmaxf(mA, mx);
        const float fct = exp2f(mA - mn);
        oAA *= fct; oBA *= fct; lA *= fct;
        mA = mn;
      }
      const float p0 = exp2f(s0[0] - mA), p1 = exp2f(s0[1] - mA);
      const float p2 = exp2f(s0[2] - mA), p3 = exp2f(s0[3] - mA);
      const float p4 = exp2f(s1[0] - mA), p5 = exp2f(s1[1] - mA);
      const float p6 = exp2f(s1[2] - mA), p7 = exp2f(s1[3] - mA);
      const float p8 = exp2f(s2[0] - mA), p9 = exp2f(s2[1] - mA);
      const float pa = exp2f(s2[2] - mA), pb = exp2f(s2[3] - mA);
      const float pc = exp2f(s3[0] - mA), pd = exp2f(s3[1] - mA);
      const float pe = exp2f(s3[2] - mA), pf = exp2f(s3[3] - mA);
      lA += (((p0 + p1) + (p2 + p3)) + ((p4 + p5) + (p6 + p7))) +
            (((p8 + p9) + (pa + pb)) + ((pc + pd) + (pe + pf)));
      UH ph0, ph1;
      ph0.h2[0] = __builtin_amdgcn_cvt_pkrtz(p0, p1);
      ph0.h2[1] = __builtin_amdgcn_cvt_pkrtz(p2, p3);
      ph0.h2[2] = __builtin_amdgcn_cvt_pkrtz(p4, p5);
      ph0.h2[3] = __builtin_amdgcn_cvt_pkrtz(p6, p7);
      ph1.h2[0] = __builtin_amdgcn_cvt_pkrtz(p8, p9);
      ph1.h2[1] = __builtin_amdgcn_cvt_pkrtz(pa, pb);
      ph1.h2[2] = __builtin_amdgcn_cvt_pkrtz(pc, pd);
      ph1.h2[3] = __builtin_amdgcn_cvt_pkrtz(pe, pf);
      oAA = __builtin_amdgcn_mfma_f32_16x16x32_f16(va0, ph0.h8, oAA, 0, 0, 0);
      oAA = __builtin_amdgcn_mfma_f32_16x16x32_f16(va1, ph1.h8, oAA, 0, 0, 0);
      oBA = __builtin_amdgcn_mfma_f32_16x16x32_f16(vb0, ph0.h8, oBA, 0, 0, 0);
      oBA = __builtin_amdgcn_mfma_f32_16x16x32_f16(vb1, ph1.h8, oBA, 0, 0, 0);
    }
    // ---- q-tile B ----
    {
      f32x4 s0 = {0.f, 0.f, 0.f, 0.f}, s1 = {0.f, 0.f, 0.f, 0.f};
      f32x4 s2 = {0.f, 0.f, 0.f, 0.f}, s3 = {0.f, 0.f, 0.f, 0.f};
      s0 = __builtin_amdgcn_mfma_f32_16x16x32_f16(k0, qfB, s0, 0, 0, 0);
      s1 = __builtin_amdgcn_mfma_f32_16x16x32_f16(k1, qfB, s1, 0, 0, 0);
      s2 = __builtin_amdgcn_mfma_f32_16x16x32_f16(k2, qfB, s2, 0, 0, 0);
      s3 = __builtin_amdgcn_mfma_f32_16x16x32_f16(k3, qfB, s3, 0, 0, 0);
      float mxl = fmaxf(fmaxf(fmaxf(s0[0], s0[1]), fmaxf(s0[2], s0[3])),
                        fmaxf(fmaxf(s1[0], s1[1]), fmaxf(s1[2], s1[3])));
      mxl = fmaxf(mxl, fmaxf(fmaxf(fmaxf(s2[0], s2[1]), fmaxf(s2[2], s2[3])),
                             fmaxf(fmaxf(s3[0], s3[1]), fmaxf(s3[2], s3[3]))));
      if (!__all(mxl <= mB)) {
        float mx = mxl;
        mx = fmaxf(mx, __shfl_xor(mx, 16, 64));
        mx = fmaxf(mx, __shfl_xor(mx, 32, 64));
        const float mn = fmaxf(mB, mx);
        const float fct = exp2f(mB - mn);
        oAB *= fct; oBB *= fct; lB *= fct;
        mB = mn;
      }
      const float p0 = exp2f(s0[0] - mB), p1 = exp2f(s0[1] - mB);
      const float p2 = exp2f(s0[2] - mB), p3 = exp2f(s0[3] - mB);
      const float p4 = exp2f(s1[0] - mB), p5 = exp2f(s1[1] - mB);
      const float p6 = exp2f(s1[2] - mB), p7 = exp2f(s1[3] - mB);
      const float p8 = exp2f(s2[0] - mB), p9 = exp2f(s2[1] - mB);
      const float pa = exp2f(s2[2] - mB), pb = exp2f(s2[3] - mB);
      const float pc = exp2f(s3[0] - mB), pd = exp2f(s3[1] - mB);
      const float pe = exp2f(s3[2] - mB), pf = exp2f(s3[3] - mB);
      lB += (((p0 + p1) + (p2 + p3)) + ((p4 + p5) + (p6 + p7))) +
            (((p8 + p9) + (pa + pb)) + ((pc + pd) + (pe + pf)));
      UH ph0, ph1;
      ph0.h2[0] = __builtin_amdgcn_cvt_pkrtz(p0, p1);
      ph0.h2[1] = __builtin_amdgcn_cvt_pkrtz(p2, p3);
      ph0.h2[2] = __builtin_amdgcn_cvt_pkrtz(p4, p5);
      ph0.h2[3] = __builtin_amdgcn_cvt_pkrtz(p6, p7);
      ph1.h2[0] = __builtin_amdgcn_cvt_pkrtz(p8, p9);
      ph1.h2[1] = __builtin_amdgcn_cvt_pkrtz(pa, pb);
      ph1.h2[2] = __builtin_amdgcn_cvt_pkrtz(pc, pd);
      ph1.h2[3] = __builtin_amdgcn_cvt_pkrtz(pe, pf);
      oAB = __builtin_amdgcn_mfma_f32_16x16x32_f16(va0, ph0.h8, oAB, 0, 0, 0);
      oAB = __builtin_amdgcn_mfma_f32_16x16x32_f16(va1, ph1.h8, oAB, 0, 0, 0);
      oBB = __builtin_amdgcn_mfma_f32_16x16x32_f16(vb0, ph0.h8, oBB, 0, 0, 0);
      oBB = __builtin_amdgcn_mfma_f32_16x16x32_f16(vb1, ph1.h8, oBB, 0, 0, 0);
    }
  }

  lA += __shfl_xor(lA, 16, 64);
  lA += __shfl_xor(lA, 32, 64);
  lB += __shfl_xor(lB, 16, 64);
  lB += __shfl_xor(lB, 32, 64);

  wave_writeout(lds, wexp, Mq, Lq, oAA, oBA, mA, lA, wid, g, li, tid, qpair * 2,
                blockIdx.y, part);
  __syncthreads();
  wave_writeout(lds, wexp, Mq, Lq, oAB, oBB, mB, lB, wid, g, li, tid, qpair * 2 + 1,
                blockIdx.y, part);
}

// ---------------- combine 8 partials + fused wo AND w4 projections -> fp16 t4 ----------------

__global__ void __launch_bounds__(256) attn_combine_wo_w4(const float* __restrict__ part,
                                                          const float* __restrict__ wo,
                                                          const float* __restrict__ bo,
                                                          const float* __restrict__ w4,
                                                          unsigned short* __restrict__ T16out) {
  __shared__ float wols[1024];
  __shared__ float w4ls[1024];
  __shared__ float bos[32];
  __shared__ float aos[4][16][33];
  __shared__ float hs[4][16][33];
  const int tid = threadIdx.x;
  for (int i = tid; i < 1024; i += 256) {
    wols[i] = wo[i];
    w4ls[i] = w4[i];
  }
  if (tid < 32) bos[tid] = bo[tid];
  const int wv = tid >> 6, lane = tid & 63;
  const int qt = blockIdx.x * 4 + wv;
  const int q = lane & 15, g = lane >> 4;
  const int pb = qt * 8 * 544;
  float ms[8], w8[8];
  float M = -1e30f;
#pragma unroll
  for (int s = 0; s < 8; ++s) {
    ms[s] = part[pb + s * 544 + 512 + q];
    M = fmaxf(M, ms[s]);
  }
  float L = 0.f;
#pragma unroll
  for (int s = 0; s < 8; ++s) {
    w8[s] = exp2f(ms[s] - M);
    L += w8[s] * part[pb + s * 544 + 528 + q];
  }
  const float invL = 1.0f / L;
#pragma unroll
  for (int r = 0; r < 8; ++r) {
    const int d = g + 4 * r;
    const int o = d * 16 + q;
    float ov = 0.f;
#pragma unroll
    for (int s = 0; s < 8; ++s) ov += w8[s] * part[pb + s * 544 + o];
    aos[wv][q][d] = ov * invL;
  }
  __syncthreads();
#pragma unroll
  for (int r = 0; r < 8; ++r) {
    const int dout = g + 4 * r;
    float acc = bos[dout];
#pragma unroll
    for (int k = 0; k < 32; ++k) acc += aos[wv][q][k] * wols[dout * 32 + k];
    hs[wv][q][dout] = acc;
  }
#pragma unroll
  for (int r = 0; r < 8; ++r) {
    const int dout = g + 4 * r;
    float acc = 0.f;
#pragma unroll
    for (int k = 0; k < 32; ++k) acc += hs[wv][q][k] * w4ls[k * 32 + dout];
    HC c;
    c.h = (_Float16)acc;
    T16out[(size_t)(qt * 16 + q) * 32 + dout] = c.u;
  }
}

// ---------------- launch ----------------

extern "C" void kernel_launch(void* const* d_in, const int* in_sizes, int n_in,
                              void* d_out, int out_size, void* d_ws, size_t ws_size,
                              hipStream_t stream) {
  (void)in_sizes; (void)n_in; (void)out_size; (void)ws_size;
  const int* adj = (const int*)d_in[0];
  const float* feat = (const float*)d_in[1];
  const float* w1 = (const float*)d_in[2];  const float* b1 = (const float*)d_in[3];
  const float* w2 = (const float*)d_in[4];  const float* b2 = (const float*)d_in[5];
  const float* w3 = (const float*)d_in[6];  const float* b3 = (const float*)d_in[7];
  const float* wqkv = (const float*)d_in[8];const float* bqkv = (const float*)d_in[9];
  const float* wo = (const float*)d_in[10]; const float* bo = (const float*)d_in[11];
  const float* w4 = (const float*)d_in[12]; const float* b4 = (const float*)d_in[13];
  const float* w5a = (const float*)d_in[14];const float* b5a = (const float*)d_in[15];
  const float* w6a = (const float*)d_in[16];const float* b6a = (const float*)d_in[17];
  const float* w7a = (const float*)d_in[18];const float* b7a = (const float*)d_in[19];
  const float* w5f = (const float*)d_in[20];const float* b5f = (const float*)d_in[21];
  const float* w6f = (const float*)d_in[22];const float* b6f = (const float*)d_in[23];
  const float* w7f = (const float*)d_in[24];const float* b7f = (const float*)d_in[25];
  float* outp = (float*)d_out;

  float* wsf = (float*)d_ws;
  int* wsi = (int*)d_ws;
  int* cnt = wsi;                 // 8192
  int* cur = wsi + 8192;          // 8192 (zeroed by scan)
  int* rp = wsi + 16384;          // 8193
  float* dinv = wsf + 24832;      // 8192
  float* wgt = wsf + 33024;       // 262144
  int* col = wsi + 295168;        // 262144
  float* T = wsf + 557312;        // 8192*128 = 1048576 f32
  float* B0 = wsf + 1605888;      // 8192*64
  float* B1 = wsf + 2130176;      // 8192*32
  float* B2 = wsf + 2392320;      // 8192*64  (end 2916608)
  unsigned short* Q16 = (unsigned short*)(wsf + 2916608);
  unsigned short* K16 = Q16 + 262144;
  unsigned short* V16 = K16 + 262144;
  // T-region fp16 temps (all dead during attention; part overlays them)
  unsigned short* T16u = (unsigned short*)T;
  unsigned short* t1 = T16u;            // 8192x64
  unsigned short* t2 = T16u + 524288;   // 8192x32
  unsigned short* t3 = T16u;            // (t1 dead)
  unsigned short* B0h = (unsigned short*)B0;  // h4 fp16 table
  unsigned short* B1h = (unsigned short*)B1;  // h5a fp16 table
  unsigned short* B2h = (unsigned short*)B2;  // h5f fp16 table
  unsigned short* h6f = T16u;                 // 8192x64 fp16 (T free post-attn)
  float* g7f = T + 262144;                    // 8192x64 f32
  float* pre7a = B1;                          // 8192x2
  // attention partials: 512 qtiles x 8 ranges x 544 f32 = 2,228,224 f32
  // spans T..B2 [557312, 2785536) — all dead during attention
  float* part = T;
  // t4 sits in the B2 tail just past part: [2785536, 2916608) = 262144 ushorts
  unsigned short* t4 = (unsigned short*)(wsf + 2785536);

  const int* src = adj;
  const int* dst = adj + N_EDGES;

  zero_kernel<<<8, 256, 0, stream>>>((int4*)cnt);  // cnt (8192 ints)
  cm_kernel<<<1536, 256, 0, stream>>>(dst, cnt, feat, w1, t1);  // count || mm1
  scan_kernel<<<1, 1024, 0, stream>>>(cnt, rp, dinv, cur);      // also zeroes cur
  fill_kernel<<<N_EDGES / 256, 256, 0, stream>>>(src, dst, rp, dinv, cur, col, wgt);

  // F1 = agg1+mm2: h1 = relu(agg(t1)+b1); t2 = h1 @ w2 (fp16)
  layer_kernel<64, 32, true, false, false, true><<<N_NODES / 4, 256, 0, stream>>>(
      t1, w2, b1, nullptr, t2, rp, col, wgt, dinv);
  // F2 = agg2+mm3: h2 = relu(agg(t2)+b2); t3 = h2 @ w3 (fp16)
  layer_kernel<32, 32, true, false, false, true><<<N_NODES / 4, 256, 0, stream>>>(
      t2, w3, b2, nullptr, t3, rp, col, wgt, dinv);
  // F3 = agg3+qkv
  agg_qkv_kernel<<<N_NODES / 4, 256, 0, stream>>>(t3, b3, wqkv, bqkv, Q16, K16, V16, rp,
                                                  col, wgt, dinv);

  // attention: KSPLIT=8, grid 2048 blocks, VGPR cap 128 (no spill)
  {
    dim3 grid(256, 8);
    attn_mfma_kernel<<<grid, 256, 0, stream>>>(Q16, K16, V16, part);
  }
  // combine(8) + wo + w4 fused -> t4 fp16
  attn_combine_wo_w4<<<128, 256, 0, stream>>>(part, wo, bo, w4, t4);

  // gcn4 gather: t4 -> h4 fp16 table
  aggv_kernel<32, true, true, true><<<N_NODES / 4, 256, 0, stream>>>(t4, rp, col, wgt,
                                                                     dinv, b4, B0h);

  // F5 = shared L5 gather + dual project
  layer5_kernel<<<N_NODES / 4, 256, 0, stream>>>(B0h, w5a, b5a, B1h, w5f, b5f, B2h, rp,
                                                 col, wgt, dinv);
  // F6 = dual L6
  layer6_kernel<<<2 * (N_NODES / 4), 256, 0, stream>>>(B1h, w6a, b6a, B0, B2h, w6f, b6f,
                                                       h6f, rp, col, wgt, dinv);
  // tails overlapped
  het1_kernel<<<64 + 2048, 256, 0, stream>>>(B0, w7a, pre7a, h6f, g7f, rp, col, wgt, dinv);
  het2_kernel<<<64 + 1024, 256, 0, stream>>>(pre7a, b7a, outp, g7f, w7f, b7f, outp + 16384,
                                             rp, col, wgt, dinv);
}

// Round 16
// 177.972 us; speedup vs baseline: 1.4104x; 1.0093x over previous
//
#include <hip/hip_runtime.h>

#define N_NODES 8192
#define N_EDGES 262144

typedef __attribute__((ext_vector_type(4))) float f32x4;
typedef _Float16 half8 __attribute__((ext_vector_type(8)));
typedef _Float16 half4v __attribute__((ext_vector_type(4)));
typedef __fp16 fp16x2 __attribute__((ext_vector_type(2)));
union UH { half8 h8; fp16x2 h2[4]; };
union HC { _Float16 h; unsigned short u; };

// ---------------- workspace zeroing (cnt only; scan zeroes cur) ----------------

__global__ void __launch_bounds__(256) zero_kernel(int4* __restrict__ p) {
  p[blockIdx.x * 256 + threadIdx.x] = make_int4(0, 0, 0, 0);
}

// ---------------- CSR build ----------------

__global__ void __launch_bounds__(1024) scan_kernel(const int* __restrict__ cnt,
                                                    int* __restrict__ rp,
                                                    float* __restrict__ dinv,
                                                    int* __restrict__ cur) {
  __shared__ int sums[1024];
  const int t = threadIdx.x;
  const int base = t * 8;
  int c[8];
  int s = 0;
#pragma unroll
  for (int i = 0; i < 8; ++i) { c[i] = cnt[base + i]; s += c[i]; cur[base + i] = 0; }
  sums[t] = s;
  __syncthreads();
  for (int off = 1; off < 1024; off <<= 1) {
    int v = (t >= off) ? sums[t - off] : 0;
    __syncthreads();
    sums[t] += v;
    __syncthreads();
  }
  int run = (t == 0) ? 0 : sums[t - 1];
#pragma unroll
  for (int i = 0; i < 8; ++i) {
    rp[base + i] = run;
    run += c[i];
    dinv[base + i] = rsqrtf((float)(c[i] + 1));
  }
  if (t == 1023) rp[N_NODES] = run;
}

__global__ void __launch_bounds__(256) fill_kernel(const int* __restrict__ src,
                                                   const int* __restrict__ dst,
                                                   const int* __restrict__ rp,
                                                   const float* __restrict__ dinv,
                                                   int* __restrict__ cur,
                                                   int* __restrict__ col,
                                                   float* __restrict__ wgt) {
  int e = blockIdx.x * 256 + threadIdx.x;
  int d = dst[e], s = src[e];
  int p = atomicAdd(&cur[d], 1);
  int at = rp[d] + p;
  col[at] = s;
  wgt[at] = dinv[s] * dinv[d];
}

// ---------------- dense matmul body (used by cm/het kernels) ----------------

template <int FIN, int FOUT, bool WT, bool BIAS, bool RELU, bool O16>
__device__ __forceinline__ void mm_body(const float* __restrict__ x,
                                        const float* __restrict__ w,
                                        const float* __restrict__ bias, void* out,
                                        int bx, int tid, float* ws, float* xs) {
  constexpr int VEC = (FOUT >= 32) ? 4 : 1;
  constexpr int TC = FOUT / VEC;
  constexpr int ROWS = 256 / TC;
  const int r0 = bx * ROWS;
  for (int i = tid; i < FIN * FOUT; i += 256) {
    int k = i / FOUT, j = i % FOUT;
    ws[i] = WT ? w[j * FIN + k] : w[i];
  }
  for (int i = tid; i < ROWS * FIN; i += 256) {
    int r = i / FIN, k = i % FIN;
    xs[r * (FIN + 1) + k] = x[(size_t)(r0 + r) * FIN + k];
  }
  __syncthreads();
  const int jc = tid % TC, r = tid / TC;
  float acc[VEC];
#pragma unroll
  for (int v = 0; v < VEC; ++v) acc[v] = 0.0f;
#pragma unroll
  for (int k = 0; k < FIN; ++k) {
    const float xv = xs[r * (FIN + 1) + k];
#pragma unroll
    for (int v = 0; v < VEC; ++v) acc[v] += xv * ws[k * FOUT + jc * VEC + v];
  }
  float oval[VEC];
#pragma unroll
  for (int v = 0; v < VEC; ++v) {
    int j = jc * VEC + v;
    float o = BIAS ? (acc[v] + bias[j]) : acc[v];
    if (RELU) o = fmaxf(o, 0.0f);
    oval[v] = o;
  }
  if constexpr (O16 && VEC == 4) {
    unsigned short* o16 = (unsigned short*)out;
    half4v pk;
#pragma unroll
    for (int v = 0; v < 4; ++v) pk[v] = (_Float16)oval[v];
    *(half4v*)&o16[(size_t)(r0 + r) * FOUT + jc * 4] = pk;
  } else {
    float* of = (float*)out;
#pragma unroll
    for (int v = 0; v < VEC; ++v) of[(size_t)(r0 + r) * FOUT + jc * VEC + v] = oval[v];
  }
}

// ---------------- GCN gather: wave gathers one node's row into LDS / global ----------------

template <int FIN, bool I16, bool GBR>
__device__ __forceinline__ void gather_row(const void* __restrict__ t,
                                           const int* __restrict__ rp,
                                           const int* __restrict__ col,
                                           const float* __restrict__ wgt,
                                           const float* __restrict__ dinv,
                                           const float* __restrict__ gbias,
                                           float* __restrict__ xrow, int n, int lane) {
  constexpr int FPL = I16 ? 8 : 4;
  constexpr int TPN = FIN / FPL;
  constexpr int EPI = 64 / TPN;
  const int eo = lane / TPN;
  const int fq = lane % TPN;
  const float di = dinv[n];
  const int rs = rp[n], re = rp[n + 1];
  float acc[FPL];
#pragma unroll
  for (int i = 0; i < FPL; ++i) acc[i] = 0.f;
  auto accum = [&](int node, float w) {
    if constexpr (I16) {
      const half8 hv = *(const half8*)((const unsigned short*)t + (size_t)node * FIN + fq * 8);
#pragma unroll
      for (int i = 0; i < 8; ++i) acc[i] += w * (float)hv[i];
    } else {
      const f32x4 v = *(const f32x4*)((const float*)t + (size_t)node * FIN + fq * 4);
#pragma unroll
      for (int i = 0; i < 4; ++i) acc[i] += w * v[i];
    }
  };
  if (eo == 0) accum(n, di * di);
  for (int e = rs + eo; e < re; e += EPI) accum(col[e], wgt[e]);
#pragma unroll
  for (int off = TPN; off < 64; off <<= 1) {
#pragma unroll
    for (int i = 0; i < FPL; ++i) acc[i] += __shfl_xor(acc[i], off, 64);
  }
  if (eo == 0) {
#pragma unroll
    for (int i = 0; i < FPL; ++i) {
      float v = acc[i];
      if (GBR) v = fmaxf(v + gbias[fq * FPL + i], 0.f);
      xrow[fq * FPL + i] = v;
    }
  }
}

// standalone gather body (agg4 + het1 gather side)
template <int F, bool BR, bool I16, bool O16>
__device__ __forceinline__ void aggv_body(const void* __restrict__ t,
                                          const int* __restrict__ rp,
                                          const int* __restrict__ col,
                                          const float* __restrict__ wgt,
                                          const float* __restrict__ dinv,
                                          const float* __restrict__ bias,
                                          void* __restrict__ out, int bx, int tid) {
  constexpr int FPL = I16 ? 8 : 4;
  constexpr int TPN = F / FPL;
  constexpr int EPI = 64 / TPN;
  const int wv = tid >> 6;
  const int lane = tid & 63;
  const int n = bx * 4 + wv;
  const int eo = lane / TPN;
  const int fq = lane % TPN;
  const float di = dinv[n];
  const int rs = rp[n], re = rp[n + 1];
  float acc[FPL];
#pragma unroll
  for (int i = 0; i < FPL; ++i) acc[i] = 0.f;
  auto accum = [&](int node, float w) {
    if constexpr (I16) {
      const half8 hv = *(const half8*)((const unsigned short*)t + (size_t)node * F + fq * 8);
#pragma unroll
      for (int i = 0; i < 8; ++i) acc[i] += w * (float)hv[i];
    } else {
      const f32x4 v = *(const f32x4*)((const float*)t + (size_t)node * F + fq * 4);
#pragma unroll
      for (int i = 0; i < 4; ++i) acc[i] += w * v[i];
    }
  };
  if (eo == 0) accum(n, di * di);
  for (int e = rs + eo; e < re; e += EPI) accum(col[e], wgt[e]);
#pragma unroll
  for (int off = TPN; off < 64; off <<= 1) {
#pragma unroll
    for (int i = 0; i < FPL; ++i) acc[i] += __shfl_xor(acc[i], off, 64);
  }
  if (eo == 0) {
    float r[FPL];
#pragma unroll
    for (int i = 0; i < FPL; ++i) {
      float v = acc[i];
      if (BR) v = fmaxf(v + bias[fq * FPL + i], 0.f);
      r[i] = v;
    }
    if constexpr (O16) {
      unsigned short* o = (unsigned short*)out;
      if constexpr (FPL == 8) {
        half8 pk;
#pragma unroll
        for (int i = 0; i < 8; ++i) pk[i] = (_Float16)r[i];
        *(half8*)&o[(size_t)n * F + fq * 8] = pk;
      } else {
        half4v p4;
#pragma unroll
        for (int i = 0; i < 4; ++i) p4[i] = (_Float16)r[i];
        *(half4v*)&o[(size_t)n * F + fq * 4] = p4;
      }
    } else {
      float* o = (float*)out;
#pragma unroll
      for (int i = 0; i < FPL; i += 4)
        *(f32x4*)&o[(size_t)n * F + fq * FPL + i] = f32x4{r[i], r[i + 1], r[i + 2], r[i + 3]};
    }
  }
}

template <int F, bool BR = true, bool I16 = false, bool O16 = false>
__global__ void __launch_bounds__(256) aggv_kernel(const void* __restrict__ t,
                                                   const int* __restrict__ rp,
                                                   const int* __restrict__ col,
                                                   const float* __restrict__ wgt,
                                                   const float* __restrict__ dinv,
                                                   const float* __restrict__ bias,
                                                   void* __restrict__ out) {
  aggv_body<F, BR, I16, O16>(t, rp, col, wgt, dinv, bias, out, blockIdx.x, threadIdx.x);
}

// ---------------- fused GCN layer: gather (4 nodes/block) -> LDS -> project ----------------

template <int FIN, int FOUT, bool GBR, bool PBIAS, bool PRELU, bool O16>
__device__ __forceinline__ void layer_body(const unsigned short* __restrict__ tin,
                                           const float* __restrict__ w,
                                           const float* __restrict__ gbias,
                                           const float* __restrict__ pbias,
                                           void* __restrict__ out, const int* rp,
                                           const int* col, const float* wgt,
                                           const float* dinv, int bx, int tid, float* ws,
                                           float* xrow) {
  for (int i = tid; i < FIN * FOUT; i += 256) ws[i] = w[i];
  const int wv = tid >> 6, lane = tid & 63;
  const int n0 = bx * 4;
  gather_row<FIN, true, GBR>(tin, rp, col, wgt, dinv, gbias, xrow + wv * FIN, n0 + wv, lane);
  __syncthreads();
  for (int idx = tid; idx < 4 * FOUT; idx += 256) {
    const int nn = idx / FOUT, j = idx % FOUT;
    float acc = PBIAS ? pbias[j] : 0.f;
    const float* xr = xrow + nn * FIN;
#pragma unroll
    for (int k = 0; k < FIN; ++k) acc += xr[k] * ws[k * FOUT + j];
    if (PRELU) acc = fmaxf(acc, 0.f);
    if constexpr (O16) {
      HC c;
      c.h = (_Float16)acc;
      ((unsigned short*)out)[(size_t)(n0 + nn) * FOUT + j] = c.u;
    } else {
      ((float*)out)[(size_t)(n0 + nn) * FOUT + j] = acc;
    }
  }
}

template <int FIN, int FOUT, bool GBR, bool PBIAS, bool PRELU, bool O16>
__global__ void __launch_bounds__(256) layer_kernel(const unsigned short* __restrict__ tin,
                                                    const float* __restrict__ w,
                                                    const float* __restrict__ gbias,
                                                    const float* __restrict__ pbias,
                                                    void* __restrict__ out,
                                                    const int* __restrict__ rp,
                                                    const int* __restrict__ col,
                                                    const float* __restrict__ wgt,
                                                    const float* __restrict__ dinv) {
  __shared__ float ws[FIN * FOUT];
  __shared__ float xrow[4 * FIN];
  layer_body<FIN, FOUT, GBR, PBIAS, PRELU, O16>(tin, w, gbias, pbias, out, rp, col, wgt,
                                                dinv, blockIdx.x, threadIdx.x, ws, xrow);
}

// F3: gather h3 + fused QKV projection (Q scaled, V transposed+kappa-swizzled)
__global__ void __launch_bounds__(256) agg_qkv_kernel(
    const unsigned short* __restrict__ t3, const float* __restrict__ b3,
    const float* __restrict__ wqkv, const float* __restrict__ bqkv,
    unsigned short* __restrict__ Q16, unsigned short* __restrict__ K16,
    unsigned short* __restrict__ V16, const int* __restrict__ rp,
    const int* __restrict__ col, const float* __restrict__ wgt,
    const float* __restrict__ dinv) {
  __shared__ float ws[32 * 96];
  __shared__ float xrow[4 * 32];
  const int tid = threadIdx.x;
  for (int i = tid; i < 3072; i += 256) {
    int k = i / 96, j = i % 96;
    ws[i] = wqkv[j * 32 + k];
  }
  const int wv = tid >> 6, lane = tid & 63;
  const int n0 = blockIdx.x * 4;
  gather_row<32, true, true>(t3, rp, col, wgt, dinv, b3, xrow + wv * 32, n0 + wv, lane);
  __syncthreads();
  const float QSCALE = 1.4426950408889634f * 0.17677669529663687f;  // log2e/sqrt(32)
  for (int idx = tid; idx < 384; idx += 256) {
    const int nn = idx / 96, j = idx % 96;
    const int row = n0 + nn;
    const float* xr = xrow + nn * 32;
    float acc = bqkv[j];
#pragma unroll
    for (int k = 0; k < 32; ++k) acc += xr[k] * ws[k * 96 + j];
    HC c;
    if (j < 32) {
      c.h = (_Float16)(acc * QSCALE);
      Q16[(size_t)row * 32 + j] = c.u;
    } else if (j < 64) {
      c.h = (_Float16)acc;
      K16[(size_t)row * 32 + (j - 32)] = c.u;
    } else {
      c.h = (_Float16)acc;
      const int ko = row & 31;
      const int slot = 8 * ((ko & 15) >> 2) + ((ko >> 4) << 2) + (ko & 3);
      V16[(size_t)(j - 64) * N_NODES + (row & ~31) + slot] = c.u;
    }
  }
}

// F5: shared raw gather of h4 + dual projection (w5a,w5f) -> fp16 tables
__global__ void __launch_bounds__(256) layer5_kernel(
    const unsigned short* __restrict__ h4, const float* __restrict__ w5a,
    const float* __restrict__ b5a, unsigned short* __restrict__ h5a,
    const float* __restrict__ w5f, const float* __restrict__ b5f,
    unsigned short* __restrict__ h5f, const int* __restrict__ rp,
    const int* __restrict__ col, const float* __restrict__ wgt,
    const float* __restrict__ dinv) {
  __shared__ float ws[2048];
  __shared__ float xrow[4 * 32];
  const int tid = threadIdx.x;
  for (int i = tid; i < 1024; i += 256) {
    ws[i] = w5a[i];
    ws[1024 + i] = w5f[i];
  }
  const int wv = tid >> 6, lane = tid & 63;
  const int n0 = blockIdx.x * 4;
  gather_row<32, true, false>(h4, rp, col, wgt, dinv, nullptr, xrow + wv * 32, n0 + wv, lane);
  __syncthreads();
  const int nn = tid >> 6;
  const int j = tid & 63;
  const int side = j >> 5, jj = j & 31;
  const float* xr = xrow + nn * 32;
  const float* wsd = ws + side * 1024;
  float acc = side ? b5f[jj] : b5a[jj];
#pragma unroll
  for (int k = 0; k < 32; ++k) acc += xr[k] * wsd[k * 32 + jj];
  acc = fmaxf(acc, 0.f);
  HC c;
  c.h = (_Float16)acc;
  unsigned short* o = side ? h5f : h5a;
  o[(size_t)(n0 + nn) * 32 + jj] = c.u;
}

// F6: dual-side fused L6 (A: h5a->h6a f32; B: h5f->h6f fp16)
__global__ void __launch_bounds__(256) layer6_kernel(
    const unsigned short* __restrict__ h5a, const float* __restrict__ w6a,
    const float* __restrict__ b6a, float* __restrict__ h6a,
    const unsigned short* __restrict__ h5f, const float* __restrict__ w6f,
    const float* __restrict__ b6f, unsigned short* __restrict__ h6f,
    const int* __restrict__ rp, const int* __restrict__ col,
    const float* __restrict__ wgt, const float* __restrict__ dinv) {
  __shared__ float ws[32 * 64];
  __shared__ float xrow[4 * 32];
  if (blockIdx.x < 2048)
    layer_body<32, 64, false, true, true, false>(h5a, w6a, nullptr, b6a, h6a, rp, col, wgt,
                                                 dinv, blockIdx.x, threadIdx.x, ws, xrow);
  else
    layer_body<32, 64, false, true, true, true>(h5f, w6f, nullptr, b6f, h6f, rp, col, wgt,
                                                dinv, blockIdx.x - 2048, threadIdx.x, ws, xrow);
}

// ---------------- hetero kernels ----------------

__global__ void __launch_bounds__(256) cm_kernel(const int* __restrict__ dst,
                                                 int* __restrict__ cnt,
                                                 const float* __restrict__ feat,
                                                 const float* __restrict__ w1,
                                                 unsigned short* __restrict__ T16) {
  __shared__ float ws[128 * 64];
  __shared__ float xs[16 * 129];
  if (blockIdx.x < 512) {
    mm_body<128, 64, false, false, false, true>(feat, w1, nullptr, T16, blockIdx.x,
                                                threadIdx.x, ws, xs);
  } else {
    int e = (blockIdx.x - 512) * 256 + threadIdx.x;
    atomicAdd(&cnt[dst[e]], 1);
  }
}

__global__ void __launch_bounds__(256) het1_kernel(
    const float* __restrict__ h6a, const float* __restrict__ w7a, float* __restrict__ pre7a,
    const unsigned short* __restrict__ h6f, float* __restrict__ g7f,
    const int* __restrict__ rp, const int* __restrict__ col,
    const float* __restrict__ wgt, const float* __restrict__ dinv) {
  __shared__ float ws[64 * 2];
  __shared__ float xs[128 * 65];
  if (blockIdx.x < 64)
    mm_body<64, 2, false, false, false, false>(h6a, w7a, nullptr, pre7a, blockIdx.x,
                                               threadIdx.x, ws, xs);
  else
    aggv_body<64, false, true, false>(h6f, rp, col, wgt, dinv, nullptr, g7f,
                                      blockIdx.x - 64, threadIdx.x);
}

__global__ void __launch_bounds__(256) het2_kernel(
    const float* __restrict__ pre7a, const float* __restrict__ b7a, float* __restrict__ outa,
    const float* __restrict__ g7f, const float* __restrict__ w7f,
    const float* __restrict__ b7f, float* __restrict__ outf,
    const int* __restrict__ rp, const int* __restrict__ col,
    const float* __restrict__ wgt, const float* __restrict__ dinv) {
  __shared__ float ws[64 * 128];
  __shared__ float xs[8 * 65];
  if (blockIdx.x < 64) {
    const int tid = threadIdx.x;
    const int n = blockIdx.x * 128 + tid / 2;
    const int f = tid & 1;
    const float di = dinv[n];
    float acc = di * di * pre7a[(size_t)n * 2 + f];
    const int rs = rp[n], re = rp[n + 1];
    for (int e = rs; e < re; ++e) {
      acc += wgt[e] * pre7a[(size_t)col[e] * 2 + f];
    }
    acc += b7a[f];
    outa[(size_t)n * 2 + f] = fmaxf(acc, 0.0f);
  } else {
    mm_body<64, 128, false, true, true, false>(g7f, w7f, b7f, outf, blockIdx.x - 64,
                                               threadIdx.x, ws, xs);
  }
}

// ---------------- MFMA flash attention: 2 q-tiles per wave, KSPLIT=4 (measured best) ----------------

__device__ __forceinline__ void wave_writeout(float (*lds)[544], float (*wexp)[16],
                                              float* Mq, float* Lq, const f32x4& o1,
                                              const f32x4& o2, float m, float l, int wid,
                                              int g, int li, int tid, int qt, int by,
                                              float* __restrict__ part) {
#pragma unroll
  for (int r = 0; r < 4; ++r) {
    lds[wid][(4 * g + r) * 16 + li] = o1[r];
    lds[wid][(16 + 4 * g + r) * 16 + li] = o2[r];
  }
  if (g == 0) {
    lds[wid][512 + li] = m;
    lds[wid][528 + li] = l;
  }
  __syncthreads();
  if (tid < 16) {
    const int q = tid;
    const float m0 = lds[0][512 + q], m1 = lds[1][512 + q];
    const float m2 = lds[2][512 + q], m3 = lds[3][512 + q];
    const float M = fmaxf(fmaxf(m0, m1), fmaxf(m2, m3));
    const float w0 = exp2f(m0 - M), w1 = exp2f(m1 - M);
    const float w2 = exp2f(m2 - M), w3 = exp2f(m3 - M);
    wexp[0][q] = w0; wexp[1][q] = w1; wexp[2][q] = w2; wexp[3][q] = w3;
    Mq[q] = M;
    Lq[q] = w0 * lds[0][528 + q] + w1 * lds[1][528 + q] +
            w2 * lds[2][528 + q] + w3 * lds[3][528 + q];
  }
  __syncthreads();
  const int base = (qt * 4 + by) * 544;
#pragma unroll
  for (int e2 = 0; e2 < 2; ++e2) {
    const int e = tid + e2 * 256;
    const int q = e & 15;
    part[base + e] = wexp[0][q] * lds[0][e] + wexp[1][q] * lds[1][e] +
                     wexp[2][q] * lds[2][e] + wexp[3][q] * lds[3][e];
  }
  if (tid < 16) {
    part[base + 512 + tid] = Mq[tid];
    part[base + 528 + tid] = Lq[tid];
  }
}

__global__ void __launch_bounds__(256, 4) attn_mfma_kernel(
    const unsigned short* __restrict__ Q16, const unsigned short* __restrict__ K16,
    const unsigned short* __restrict__ V16, float* __restrict__ part) {
  __shared__ float lds[4][544];
  __shared__ float wexp[4][16];
  __shared__ float Mq[16], Lq[16];
  const int tid = threadIdx.x;
  const int wid = tid >> 6;
  const int lane = tid & 63;
  const int g = lane >> 4;
  const int li = lane & 15;
  const int qpair = blockIdx.x;
  const int q0A = qpair * 32;
  const int q0B = q0A + 16;
  const int kbeg = blockIdx.y * 2048 + wid * 512;

  const half8 qfA = *(const half8*)&Q16[(q0A + li) * 32 + 8 * g];
  const half8 qfB = *(const half8*)&Q16[(q0B + li) * 32 + 8 * g];
  const int koff = li * 32 + 8 * g;
  const int vA = li * N_NODES + 8 * g;
  const int vB = (16 + li) * N_NODES + 8 * g;

  f32x4 oAA = {0.f, 0.f, 0.f, 0.f}, oBA = {0.f, 0.f, 0.f, 0.f};
  f32x4 oAB = {0.f, 0.f, 0.f, 0.f}, oBB = {0.f, 0.f, 0.f, 0.f};
  float mA = -1e30f, lA = 0.f, mB = -1e30f, lB = 0.f;

  for (int t = kbeg; t < kbeg + 512; t += 64) {
    const half8 k0 = *(const half8*)&K16[(t)*32 + koff];
    const half8 k1 = *(const half8*)&K16[(t + 16) * 32 + koff];
    const half8 k2 = *(const half8*)&K16[(t + 32) * 32 + koff];
    const half8 k3 = *(const half8*)&K16[(t + 48) * 32 + koff];
    const half8 va0 = *(const half8*)&V16[vA + t];
    const half8 vb0 = *(const half8*)&V16[vB + t];
    const half8 va1 = *(const half8*)&V16[vA + t + 32];
    const half8 vb1 = *(const half8*)&V16[vB + t + 32];

    // ---- q-tile A ----
    {
      f32x4 s0 = {0.f, 0.f, 0.f, 0.f}, s1 = {0.f, 0.f, 0.f, 0.f};
      f32x4 s2 = {0.f, 0.f, 0.f, 0.f}, s3 = {0.f, 0.f, 0.f, 0.f};
      s0 = __builtin_amdgcn_mfma_f32_16x16x32_f16(k0, qfA, s0, 0, 0, 0);
      s1 = __builtin_amdgcn_mfma_f32_16x16x32_f16(k1, qfA, s1, 0, 0, 0);
      s2 = __builtin_amdgcn_mfma_f32_16x16x32_f16(k2, qfA, s2, 0, 0, 0);
      s3 = __builtin_amdgcn_mfma_f32_16x16x32_f16(k3, qfA, s3, 0, 0, 0);
      float mxl = fmaxf(fmaxf(fmaxf(s0[0], s0[1]), fmaxf(s0[2], s0[3])),
                        fmaxf(fmaxf(s1[0], s1[1]), fmaxf(s1[2], s1[3])));
      mxl = fmaxf(mxl, fmaxf(fmaxf(fmaxf(s2[0], s2[1]), fmaxf(s2[2], s2[3])),
                             fmaxf(fmaxf(s3[0], s3[1]), fmaxf(s3[2], s3[3]))));
      if (!__all(mxl <= mA)) {
        float mx = mxl;
        mx = fmaxf(mx, __shfl_xor(mx, 16, 64));
        mx = fmaxf(mx, __shfl_xor(mx, 32, 64));
        const float mn = fmaxf(mA, mx);
        const float fct = exp2f(mA - mn);
        oAA *= fct; oBA *= fct; lA *= fct;
        mA = mn;
      }
      const float p0 = exp2f(s0[0] - mA), p1 = exp2f(s0[1] - mA);
      const float p2 = exp2f(s0[2] - mA), p3 = exp2f(s0[3] - mA);
      const float p4 = exp2f(s1[0] - mA), p5 = exp2f(s1[1] - mA);
      const float p6 = exp2f(s1[2] - mA), p7 = exp2f(s1[3] - mA);
      const float p8 = exp2f(s2[0] - mA), p9 = exp2f(s2[1] - mA);
      const float pa = exp2f(s2[2] - mA), pb = exp2f(s2[3] - mA);
      const float pc = exp2f(s3[0] - mA), pd = exp2f(s3[1] - mA);
      const float pe = exp2f(s3[2] - mA), pf = exp2f(s3[3] - mA);
      lA += (((p0 + p1) + (p2 + p3)) + ((p4 + p5) + (p6 + p7))) +
            (((p8 + p9) + (pa + pb)) + ((pc + pd) + (pe + pf)));
      UH ph0, ph1;
      ph0.h2[0] = __builtin_amdgcn_cvt_pkrtz(p0, p1);
      ph0.h2[1] = __builtin_amdgcn_cvt_pkrtz(p2, p3);
      ph0.h2[2] = __builtin_amdgcn_cvt_pkrtz(p4, p5);
      ph0.h2[3] = __builtin_amdgcn_cvt_pkrtz(p6, p7);
      ph1.h2[0] = __builtin_amdgcn_cvt_pkrtz(p8, p9);
      ph1.h2[1] = __builtin_amdgcn_cvt_pkrtz(pa, pb);
      ph1.h2[2] = __builtin_amdgcn_cvt_pkrtz(pc, pd);
      ph1.h2[3] = __builtin_amdgcn_cvt_pkrtz(pe, pf);
      oAA = __builtin_amdgcn_mfma_f32_16x16x32_f16(va0, ph0.h8, oAA, 0, 0, 0);
      oAA = __builtin_amdgcn_mfma_f32_16x16x32_f16(va1, ph1.h8, oAA, 0, 0, 0);
      oBA = __builtin_amdgcn_mfma_f32_16x16x32_f16(vb0, ph0.h8, oBA, 0, 0, 0);
      oBA = __builtin_amdgcn_mfma_f32_16x16x32_f16(vb1, ph1.h8, oBA, 0, 0, 0);
    }
    // ---- q-tile B ----
    {
      f32x4 s0 = {0.f, 0.f, 0.f, 0.f}, s1 = {0.f, 0.f, 0.f, 0.f};
      f32x4 s2 = {0.f, 0.f, 0.f, 0.f}, s3 = {0.f, 0.f, 0.f, 0.f};
      s0 = __builtin_amdgcn_mfma_f32_16x16x32_f16(k0, qfB, s0, 0, 0, 0);
      s1 = __builtin_amdgcn_mfma_f32_16x16x32_f16(k1, qfB, s1, 0, 0, 0);
      s2 = __builtin_amdgcn_mfma_f32_16x16x32_f16(k2, qfB, s2, 0, 0, 0);
      s3 = __builtin_amdgcn_mfma_f32_16x16x32_f16(k3, qfB, s3, 0, 0, 0);
      float mxl = fmaxf(fmaxf(fmaxf(s0[0], s0[1]), fmaxf(s0[2], s0[3])),
                        fmaxf(fmaxf(s1[0], s1[1]), fmaxf(s1[2], s1[3])));
      mxl = fmaxf(mxl, fmaxf(fmaxf(fmaxf(s2[0], s2[1]), fmaxf(s2[2], s2[3])),
                             fmaxf(fmaxf(s3[0], s3[1]), fmaxf(s3[2], s3[3]))));
      if (!__all(mxl <= mB)) {
        float mx = mxl;
        mx = fmaxf(mx, __shfl_xor(mx, 16, 64));
        mx = fmaxf(mx, __shfl_xor(mx, 32, 64));
        const float mn = fmaxf(mB, mx);
        const float fct = exp2f(mB - mn);
        oAB *= fct; oBB *= fct; lB *= fct;
        mB = mn;
      }
      const float p0 = exp2f(s0[0] - mB), p1 = exp2f(s0[1] - mB);
      const float p2 = exp2f(s0[2] - mB), p3 = exp2f(s0[3] - mB);
      const float p4 = exp2f(s1[0] - mB), p5 = exp2f(s1[1] - mB);
      const float p6 = exp2f(s1[2] - mB), p7 = exp2f(s1[3] - mB);
      const float p8 = exp2f(s2[0] - mB), p9 = exp2f(s2[1] - mB);
      const float pa = exp2f(s2[2] - mB), pb = exp2f(s2[3] - mB);
      const float pc = exp2f(s3[0] - mB), pd = exp2f(s3[1] - mB);
      const float pe = exp2f(s3[2] - mB), pf = exp2f(s3[3] - mB);
      lB += (((p0 + p1) + (p2 + p3)) + ((p4 + p5) + (p6 + p7))) +
            (((p8 + p9) + (pa + pb)) + ((pc + pd) + (pe + pf)));
      UH ph0, ph1;
      ph0.h2[0] = __builtin_amdgcn_cvt_pkrtz(p0, p1);
      ph0.h2[1] = __builtin_amdgcn_cvt_pkrtz(p2, p3);
      ph0.h2[2] = __builtin_amdgcn_cvt_pkrtz(p4, p5);
      ph0.h2[3] = __builtin_amdgcn_cvt_pkrtz(p6, p7);
      ph1.h2[0] = __builtin_amdgcn_cvt_pkrtz(p8, p9);
      ph1.h2[1] = __builtin_amdgcn_cvt_pkrtz(pa, pb);
      ph1.h2[2] = __builtin_amdgcn_cvt_pkrtz(pc, pd);
      ph1.h2[3] = __builtin_amdgcn_cvt_pkrtz(pe, pf);
      oAB = __builtin_amdgcn_mfma_f32_16x16x32_f16(va0, ph0.h8, oAB, 0, 0, 0);
      oAB = __builtin_amdgcn_mfma_f32_16x16x32_f16(va1, ph1.h8, oAB, 0, 0, 0);
      oBB = __builtin_amdgcn_mfma_f32_16x16x32_f16(vb0, ph0.h8, oBB, 0, 0, 0);
      oBB = __builtin_amdgcn_mfma_f32_16x16x32_f16(vb1, ph1.h8, oBB, 0, 0, 0);
    }
  }

  lA += __shfl_xor(lA, 16, 64);
  lA += __shfl_xor(lA, 32, 64);
  lB += __shfl_xor(lB, 16, 64);
  lB += __shfl_xor(lB, 32, 64);

  wave_writeout(lds, wexp, Mq, Lq, oAA, oBA, mA, lA, wid, g, li, tid, qpair * 2,
                blockIdx.y, part);
  __syncthreads();
  wave_writeout(lds, wexp, Mq, Lq, oAB, oBB, mB, lB, wid, g, li, tid, qpair * 2 + 1,
                blockIdx.y, part);
}

// ---------------- combine 4 partials + fused wo AND w4 projections -> fp16 t4 ----------------

__global__ void __launch_bounds__(256) attn_combine_wo_w4(const float* __restrict__ part,
                                                          const float* __restrict__ wo,
                                                          const float* __restrict__ bo,
                                                          const float* __restrict__ w4,
                                                          unsigned short* __restrict__ T16out) {
  __shared__ float wols[1024];
  __shared__ float w4ls[1024];
  __shared__ float bos[32];
  __shared__ float aos[4][16][33];
  __shared__ float hs[4][16][33];
  const int tid = threadIdx.x;
  for (int i = tid; i < 1024; i += 256) {
    wols[i] = wo[i];
    w4ls[i] = w4[i];
  }
  if (tid < 32) bos[tid] = bo[tid];
  const int wv = tid >> 6, lane = tid & 63;
  const int qt = blockIdx.x * 4 + wv;
  const int q = lane & 15, g = lane >> 4;
  const int pb = qt * 4 * 544;
  const float m0 = part[pb + 512 + q], m1 = part[pb + 544 + 512 + q];
  const float m2 = part[pb + 1088 + 512 + q], m3 = part[pb + 1632 + 512 + q];
  const float M = fmaxf(fmaxf(m0, m1), fmaxf(m2, m3));
  const float w0 = exp2f(m0 - M), w1 = exp2f(m1 - M);
  const float w2 = exp2f(m2 - M), w3 = exp2f(m3 - M);
  const float L = w0 * part[pb + 528 + q] + w1 * part[pb + 544 + 528 + q] +
                  w2 * part[pb + 1088 + 528 + q] + w3 * part[pb + 1632 + 528 + q];
  const float invL = 1.0f / L;
#pragma unroll
  for (int r = 0; r < 8; ++r) {
    const int d = g + 4 * r;
    const int o = d * 16 + q;
    const float ov = w0 * part[pb + o] + w1 * part[pb + 544 + o] +
                     w2 * part[pb + 1088 + o] + w3 * part[pb + 1632 + o];
    aos[wv][q][d] = ov * invL;
  }
  __syncthreads();
#pragma unroll
  for (int r = 0; r < 8; ++r) {
    const int dout = g + 4 * r;
    float acc = bos[dout];
#pragma unroll
    for (int k = 0; k < 32; ++k) acc += aos[wv][q][k] * wols[dout * 32 + k];
    hs[wv][q][dout] = acc;
  }
#pragma unroll
  for (int r = 0; r < 8; ++r) {
    const int dout = g + 4 * r;
    float acc = 0.f;
#pragma unroll
    for (int k = 0; k < 32; ++k) acc += hs[wv][q][k] * w4ls[k * 32 + dout];
    HC c;
    c.h = (_Float16)acc;
    T16out[(size_t)(qt * 16 + q) * 32 + dout] = c.u;
  }
}

// ---------------- launch ----------------

extern "C" void kernel_launch(void* const* d_in, const int* in_sizes, int n_in,
                              void* d_out, int out_size, void* d_ws, size_t ws_size,
                              hipStream_t stream) {
  (void)in_sizes; (void)n_in; (void)out_size; (void)ws_size;
  const int* adj = (const int*)d_in[0];
  const float* feat = (const float*)d_in[1];
  const float* w1 = (const float*)d_in[2];  const float* b1 = (const float*)d_in[3];
  const float* w2 = (const float*)d_in[4];  const float* b2 = (const float*)d_in[5];
  const float* w3 = (const float*)d_in[6];  const float* b3 = (const float*)d_in[7];
  const float* wqkv = (const float*)d_in[8];const float* bqkv = (const float*)d_in[9];
  const float* wo = (const float*)d_in[10]; const float* bo = (const float*)d_in[11];
  const float* w4 = (const float*)d_in[12]; const float* b4 = (const float*)d_in[13];
  const float* w5a = (const float*)d_in[14];const float* b5a = (const float*)d_in[15];
  const float* w6a = (const float*)d_in[16];const float* b6a = (const float*)d_in[17];
  const float* w7a = (const float*)d_in[18];const float* b7a = (const float*)d_in[19];
  const float* w5f = (const float*)d_in[20];const float* b5f = (const float*)d_in[21];
  const float* w6f = (const float*)d_in[22];const float* b6f = (const float*)d_in[23];
  const float* w7f = (const float*)d_in[24];const float* b7f = (const float*)d_in[25];
  float* outp = (float*)d_out;

  float* wsf = (float*)d_ws;
  int* wsi = (int*)d_ws;
  int* cnt = wsi;                 // 8192
  int* cur = wsi + 8192;          // 8192 (zeroed by scan)
  int* rp = wsi + 16384;          // 8193
  float* dinv = wsf + 24832;      // 8192
  float* wgt = wsf + 33024;       // 262144
  int* col = wsi + 295168;        // 262144
  float* T = wsf + 557312;        // 8192*128 = 1048576 f32
  float* B0 = wsf + 1605888;      // 8192*64
  float* B1 = wsf + 2130176;      // 8192*32
  float* B2 = wsf + 2392320;      // 8192*64  (end 2916608)
  unsigned short* Q16 = (unsigned short*)(wsf + 2916608);
  unsigned short* K16 = Q16 + 262144;
  unsigned short* V16 = K16 + 262144;
  // T-region fp16 temps (all dead during attention; part overlays them)
  unsigned short* T16u = (unsigned short*)T;
  unsigned short* t1 = T16u;            // 8192x64
  unsigned short* t2 = T16u + 524288;   // 8192x32
  unsigned short* t3 = T16u;            // (t1 dead)
  unsigned short* t4 = (unsigned short*)B2;   // 8192x32 (B2 free; dead before L5 writes h5f)
  unsigned short* B0h = (unsigned short*)B0;  // h4 fp16 table
  unsigned short* B1h = (unsigned short*)B1;  // h5a fp16 table
  unsigned short* B2h = (unsigned short*)B2;  // h5f fp16 table
  unsigned short* h6f = T16u;                 // 8192x64 fp16 (T free post-attn)
  float* g7f = T + 262144;                    // 8192x64 f32
  float* pre7a = B1;                          // 8192x2
  float* part = T;  // 512 qtiles x 4 ranges x 544 f32 (spills into B0 head; t3 dead then)

  const int* src = adj;
  const int* dst = adj + N_EDGES;

  zero_kernel<<<8, 256, 0, stream>>>((int4*)cnt);  // cnt (8192 ints)
  cm_kernel<<<1536, 256, 0, stream>>>(dst, cnt, feat, w1, t1);  // count || mm1
  scan_kernel<<<1, 1024, 0, stream>>>(cnt, rp, dinv, cur);      // also zeroes cur
  fill_kernel<<<N_EDGES / 256, 256, 0, stream>>>(src, dst, rp, dinv, cur, col, wgt);

  // F1 = agg1+mm2: h1 = relu(agg(t1)+b1); t2 = h1 @ w2 (fp16)
  layer_kernel<64, 32, true, false, false, true><<<N_NODES / 4, 256, 0, stream>>>(
      t1, w2, b1, nullptr, t2, rp, col, wgt, dinv);
  // F2 = agg2+mm3: h2 = relu(agg(t2)+b2); t3 = h2 @ w3 (fp16)
  layer_kernel<32, 32, true, false, false, true><<<N_NODES / 4, 256, 0, stream>>>(
      t2, w3, b2, nullptr, t3, rp, col, wgt, dinv);
  // F3 = agg3+qkv
  agg_qkv_kernel<<<N_NODES / 4, 256, 0, stream>>>(t3, b3, wqkv, bqkv, Q16, K16, V16, rp,
                                                  col, wgt, dinv);

  // attention: KSPLIT=4 (measured best)
  {
    dim3 grid(256, 4);
    attn_mfma_kernel<<<grid, 256, 0, stream>>>(Q16, K16, V16, part);
  }
  // combine(4) + wo + w4 fused -> t4 fp16 (B2 region; no overlap with part)
  attn_combine_wo_w4<<<128, 256, 0, stream>>>(part, wo, bo, w4, t4);

  // gcn4 gather: t4 -> h4 fp16 table
  aggv_kernel<32, true, true, true><<<N_NODES / 4, 256, 0, stream>>>(t4, rp, col, wgt,
                                                                     dinv, b4, B0h);

  // F5 = shared L5 gather + dual project
  layer5_kernel<<<N_NODES / 4, 256, 0, stream>>>(B0h, w5a, b5a, B1h, w5f, b5f, B2h, rp,
                                                 col, wgt, dinv);
  // F6 = dual L6
  layer6_kernel<<<2 * (N_NODES / 4), 256, 0, stream>>>(B1h, w6a, b6a, B0, B2h, w6f, b6f,
                                                       h6f, rp, col, wgt, dinv);
  // tails overlapped
  het1_kernel<<<64 + 2048, 256, 0, stream>>>(B0, w7a, pre7a, h6f, g7f, rp, col, wgt, dinv);
  het2_kernel<<<64 + 1024, 256, 0, stream>>>(pre7a, b7a, outp, g7f, w7f, b7f, outp + 16384,
                                             rp, col, wgt, dinv);
}